// Round 6
// baseline (1291.917 us; speedup 1.0000x reference)
//
#include <hip/hip_runtime.h>
#include <hip/hip_bf16.h>
#include <math.h>

#define EPSF 1e-5f

__device__ __forceinline__ float gelu_f(float z){
  return 0.5f*z*(1.0f + erff(z*0.70710678118654752f));
}

// ---------------- copy ----------------
__global__ void copy4_k(const float* __restrict__ s, float* __restrict__ d){
  long i = (long)blockIdx.x*blockDim.x + threadIdx.x;
  reinterpret_cast<float4*>(d)[i] = reinterpret_cast<const float4*>(s)[i];
}

// ---------------- LayerNorm (one row of 256 per block) ----------------
__global__ void ln_k(const float* __restrict__ x, const float* __restrict__ g,
                     const float* __restrict__ b, float* __restrict__ out){
  const int row = blockIdx.x;
  const int t = threadIdx.x;
  float v = x[(long)row*256 + t];
  float s = v, s2 = v*v;
  for (int o=32;o>0;o>>=1){ s += __shfl_down(s,o); s2 += __shfl_down(s2,o); }
  __shared__ float ls[4], ls2[4];
  const int w = t>>6, lane = t&63;
  if (lane==0){ ls[w]=s; ls2[w]=s2; }
  __syncthreads();
  if (t==0){
    float a  = ls[0]+ls[1]+ls[2]+ls[3];
    float a2 = ls2[0]+ls2[1]+ls2[2]+ls2[3];
    float mu = a*(1.f/256.f);
    float var = a2*(1.f/256.f) - mu*mu;
    ls[0]=mu; ls2[0]=rsqrtf(var+EPSF);
  }
  __syncthreads();
  const float mu = ls[0], rstd = ls2[0];
  out[(long)row*256+t] = (v-mu)*rstd*g[t] + b[t];
}

// ---------------- generic fp32 GEMM: C = act(A@B + bias + res) ----------------
template<int BM,int BN,int BK,int TM,int TN,int ACT,bool RES,bool BIAS>
__global__ __launch_bounds__(256)
void gemm_k(const float* __restrict__ A, int lda,
            const float* __restrict__ B, int ldb,
            float* __restrict__ C, int ldc,
            const float* __restrict__ bias,
            const float* __restrict__ res,
            int K)
{
  __shared__ float As[BK][BM+4];
  __shared__ float Bs[BK][BN+4];
  const int tid = threadIdx.x;
  const int n0 = blockIdx.x * BN;
  const int m0 = blockIdx.y * BM;

  float acc[TM][TN];
  #pragma unroll
  for (int i=0;i<TM;i++)
    #pragma unroll
    for (int j=0;j<TN;j++) acc[i][j]=0.f;

  constexpr int TCOLS = BN/TN;
  const int tcol = tid % TCOLS, trow = tid / TCOLS;
  const int tm0 = trow*TM, tn0 = tcol*TN;

  for (int k0=0;k0<K;k0+=BK){
    constexpr int KQ = BK/4;
    for (int i=tid; i<BM*KQ; i+=256){
      int m = i/KQ, kq = (i%KQ)*4;
      float4 a4 = *reinterpret_cast<const float4*>(A + (long)(m0+m)*lda + (k0+kq));
      As[kq+0][m]=a4.x; As[kq+1][m]=a4.y; As[kq+2][m]=a4.z; As[kq+3][m]=a4.w;
    }
    constexpr int NQ = BN/4;
    for (int i=tid; i<BK*NQ; i+=256){
      int k = i/NQ, nq = (i%NQ)*4;
      *reinterpret_cast<float4*>(&Bs[k][nq]) =
        *reinterpret_cast<const float4*>(B + (long)(k0+k)*ldb + (n0+nq));
    }
    __syncthreads();
    #pragma unroll
    for (int kk=0;kk<BK;kk++){
      float a[TM], bfr[TN];
      #pragma unroll
      for (int i=0;i<TM;i+=4)
        *reinterpret_cast<float4*>(&a[i]) = *reinterpret_cast<const float4*>(&As[kk][tm0+i]);
      #pragma unroll
      for (int j=0;j<TN;j+=4)
        *reinterpret_cast<float4*>(&bfr[j]) = *reinterpret_cast<const float4*>(&Bs[kk][tn0+j]);
      #pragma unroll
      for (int i=0;i<TM;i++)
        #pragma unroll
        for (int j=0;j<TN;j++)
          acc[i][j] = fmaf(a[i], bfr[j], acc[i][j]);
    }
    __syncthreads();
  }

  #pragma unroll
  for (int i=0;i<TM;i++){
    const long rowoff = (long)(m0+tm0+i)*ldc + n0;
    #pragma unroll
    for (int j=0;j<TN;j+=4){
      float4 v;
      v.x = acc[i][j+0]; v.y = acc[i][j+1]; v.z = acc[i][j+2]; v.w = acc[i][j+3];
      if (BIAS){
        float4 bb = *reinterpret_cast<const float4*>(bias + (n0+tn0+j));
        v.x+=bb.x; v.y+=bb.y; v.z+=bb.z; v.w+=bb.w;
      }
      if (RES){
        float4 r4 = *reinterpret_cast<const float4*>(res + rowoff + tn0 + j);
        v.x+=r4.x; v.y+=r4.y; v.z+=r4.z; v.w+=r4.w;
      }
      if (ACT==1){
        v.x=gelu_f(v.x); v.y=gelu_f(v.y); v.z=gelu_f(v.z); v.w=gelu_f(v.w);
      }
      *reinterpret_cast<float4*>(C + rowoff + tn0 + j) = v;
    }
  }
}

// ---------------- fused flash attention (52 KB LDS: P reuses Ks) ----------------
// qkv: [B*N][768] (q cols 0..255, k 256..511, v 512..767; col = h*64+d)
// o:   [B*N][256] merged
// grid: (16 q-tiles, 32 bh), block 256.
__global__ __launch_bounds__(256)
void attn_k(const float* __restrict__ qkv, float* __restrict__ o){
  const int q0 = blockIdx.x * 64;
  const int bh = blockIdx.y;
  const int b = bh >> 2, h = bh & 3;
  const int tid = threadIdx.x;
  const int tcol = tid & 15;
  const int trow = tid >> 4;

  __shared__ float Qs[64][68];
  __shared__ float Ks[64][68];   // doubles as P after S-compute
  __shared__ float Vs[64][68];

  const long rowbase = (long)b*1024;
  for (int f = tid; f < 1024; f += 256){
    int r = f >> 4, d4 = (f & 15) << 2;
    *reinterpret_cast<float4*>(&Qs[r][d4]) =
      *reinterpret_cast<const float4*>(qkv + (rowbase + q0 + r)*768 + h*64 + d4);
  }

  float m_i[4], l_i[4], acc[4][4];
  #pragma unroll
  for (int r=0;r<4;r++){
    m_i[r] = -1e30f; l_i[r] = 0.f;
    #pragma unroll
    for (int c=0;c<4;c++) acc[r][c] = 0.f;
  }

  for (int k0 = 0; k0 < 1024; k0 += 64){
    __syncthreads();   // prev-iter PV reads done; Q-load visible (iter 0)
    for (int f = tid; f < 1024; f += 256){
      int r = f >> 4, d4 = (f & 15) << 2;
      const float* src = qkv + (rowbase + k0 + r)*768 + h*64 + d4;
      *reinterpret_cast<float4*>(&Ks[r][d4]) = *reinterpret_cast<const float4*>(src + 256);
      *reinterpret_cast<float4*>(&Vs[r][d4]) = *reinterpret_cast<const float4*>(src + 512);
    }
    __syncthreads();

    float s[4][4];
    #pragma unroll
    for (int r=0;r<4;r++)
      #pragma unroll
      for (int j=0;j<4;j++) s[r][j] = 0.f;

    #pragma unroll
    for (int d4=0; d4<64; d4+=4){
      float4 q4[4], k4[4];
      #pragma unroll
      for (int rr=0;rr<4;rr++)
        q4[rr] = *reinterpret_cast<const float4*>(&Qs[4*trow+rr][d4]);
      #pragma unroll
      for (int jj=0;jj<4;jj++)
        k4[jj] = *reinterpret_cast<const float4*>(&Ks[tcol+16*jj][d4]);
      #pragma unroll
      for (int rr=0;rr<4;rr++)
        #pragma unroll
        for (int jj=0;jj<4;jj++){
          s[rr][jj] = fmaf(q4[rr].x, k4[jj].x, s[rr][jj]);
          s[rr][jj] = fmaf(q4[rr].y, k4[jj].y, s[rr][jj]);
          s[rr][jj] = fmaf(q4[rr].z, k4[jj].z, s[rr][jj]);
          s[rr][jj] = fmaf(q4[rr].w, k4[jj].w, s[rr][jj]);
        }
    }

    float pl[4][4];
    #pragma unroll
    for (int rr=0;rr<4;rr++){
      float mx = -1e30f;
      #pragma unroll
      for (int jj=0;jj<4;jj++){ s[rr][jj] *= 0.125f; mx = fmaxf(mx, s[rr][jj]); }
      #pragma unroll
      for (int off=8; off>0; off>>=1) mx = fmaxf(mx, __shfl_xor(mx, off));
      const float mnew = fmaxf(m_i[rr], mx);
      const float alpha = __expf(m_i[rr] - mnew);
      m_i[rr] = mnew;
      float rs = 0.f;
      #pragma unroll
      for (int jj=0;jj<4;jj++){
        float p = __expf(s[rr][jj] - mnew);
        pl[rr][jj] = p; rs += p;
      }
      #pragma unroll
      for (int off=8; off>0; off>>=1) rs += __shfl_xor(rs, off);
      l_i[rr] = l_i[rr]*alpha + rs;
      #pragma unroll
      for (int c=0;c<4;c++) acc[rr][c] *= alpha;
    }

    __syncthreads();   // all waves done reading Ks for S -> safe to overwrite with P
    #pragma unroll
    for (int rr=0;rr<4;rr++)
      #pragma unroll
      for (int jj=0;jj<4;jj++)
        Ks[4*trow+rr][tcol+16*jj] = pl[rr][jj];
    // P rows [4*trow..4*trow+3] are written & read by the same wave (in-order DS).

    #pragma unroll
    for (int j4=0;j4<64;j4+=4){
      float4 p4[4], v4[4];
      #pragma unroll
      for (int rr=0;rr<4;rr++)
        p4[rr] = *reinterpret_cast<const float4*>(&Ks[4*trow+rr][j4]);
      #pragma unroll
      for (int jj=0;jj<4;jj++)
        v4[jj] = *reinterpret_cast<const float4*>(&Vs[j4+jj][4*tcol]);
      #pragma unroll
      for (int rr=0;rr<4;rr++){
        acc[rr][0] = fmaf(p4[rr].x, v4[0].x, acc[rr][0]);
        acc[rr][1] = fmaf(p4[rr].x, v4[0].y, acc[rr][1]);
        acc[rr][2] = fmaf(p4[rr].x, v4[0].z, acc[rr][2]);
        acc[rr][3] = fmaf(p4[rr].x, v4[0].w, acc[rr][3]);
        acc[rr][0] = fmaf(p4[rr].y, v4[1].x, acc[rr][0]);
        acc[rr][1] = fmaf(p4[rr].y, v4[1].y, acc[rr][1]);
        acc[rr][2] = fmaf(p4[rr].y, v4[1].z, acc[rr][2]);
        acc[rr][3] = fmaf(p4[rr].y, v4[1].w, acc[rr][3]);
        acc[rr][0] = fmaf(p4[rr].z, v4[2].x, acc[rr][0]);
        acc[rr][1] = fmaf(p4[rr].z, v4[2].y, acc[rr][1]);
        acc[rr][2] = fmaf(p4[rr].z, v4[2].z, acc[rr][2]);
        acc[rr][3] = fmaf(p4[rr].z, v4[2].w, acc[rr][3]);
        acc[rr][0] = fmaf(p4[rr].w, v4[3].x, acc[rr][0]);
        acc[rr][1] = fmaf(p4[rr].w, v4[3].y, acc[rr][1]);
        acc[rr][2] = fmaf(p4[rr].w, v4[3].z, acc[rr][2]);
        acc[rr][3] = fmaf(p4[rr].w, v4[3].w, acc[rr][3]);
      }
    }
  }

  #pragma unroll
  for (int rr=0;rr<4;rr++){
    const float inv = 1.f / l_i[rr];
    float4 v;
    v.x = acc[rr][0]*inv; v.y = acc[rr][1]*inv;
    v.z = acc[rr][2]*inv; v.w = acc[rr][3]*inv;
    *reinterpret_cast<float4*>(o + (rowbase + q0 + 4*trow + rr)*256 + h*64 + 4*tcol) = v;
  }
}

// ---------------- SE gate helpers ----------------
__global__ void semean1_k(const float* __restrict__ x, float* __restrict__ part){
  const int blk = blockIdx.x; const int b = blk>>3, sl = blk&7;
  const int t = threadIdx.x;
  const float* p = x + ((long)b*1024 + sl*128)*256 + t;
  float s=0.f;
  for (int i=0;i<128;i++) s += p[(long)i*256];
  part[(long)blk*256 + t] = s;
}

__global__ void semean2_k(const float* __restrict__ part, float* __restrict__ cm){
  const int b = blockIdx.x, t = threadIdx.x;
  float s=0.f;
  for (int i=0;i<8;i++) s += part[(long)(b*8+i)*256 + t];
  cm[b*256+t] = s*(1.f/1024.f);
}

__global__ void segate_k(const float* __restrict__ cm, const float* __restrict__ w1,
                         const float* __restrict__ w2, float* __restrict__ gate){
  const int b = blockIdx.x, t = threadIdx.x;
  __shared__ float sc[256], sh[64];
  sc[t] = cm[b*256+t];
  __syncthreads();
  if (t < 64){
    float s=0.f;
    for (int k=0;k<256;k++) s += sc[k]*w1[k*64+t];
    sh[t] = fmaxf(s, 0.f);
  }
  __syncthreads();
  float s=0.f;
  for (int k=0;k<64;k++) s += sh[k]*w2[k*256+t];
  gate[b*256+t] = 1.f/(1.f+__expf(-s));
}

__global__ void seapply_k(float* __restrict__ x, const float* __restrict__ gate){
  long o4 = ((long)blockIdx.x*256 + threadIdx.x)*4;
  float4 v = *reinterpret_cast<float4*>(x+o4);
  float4 g = *reinterpret_cast<const float4*>(gate + (((o4>>18)<<8) | (o4 & 255)));
  v.x*=g.x; v.y*=g.y; v.z*=g.z; v.w*=g.w;
  *reinterpret_cast<float4*>(x+o4) = v;
}

// ---------------- depthwise conv (1x3 over tokens) + BN + GELU ----------------
__global__ void conv_k(const float* __restrict__ y, float* __restrict__ z,
   const float* __restrict__ wh, const float* __restrict__ bh,
   const float* __restrict__ wv, const float* __restrict__ bv,
   const float* __restrict__ g, const float* __restrict__ bb,
   const float* __restrict__ mm, const float* __restrict__ vv)
{
  const int row = blockIdx.x;
  const int n = row & 1023;
  const float* yr = y + (long)row*512;
  for (int j=threadIdx.x; j<512; j+=256){
    float yc = yr[j];
    float ym = (n>0)   ? yr[j-512] : 0.f;
    float yp = (n<1023)? yr[j+512] : 0.f;
    float chv = wh[j*3+0]*ym + wh[j*3+1]*yc + wh[j*3+2]*yp + bh[j];
    float cvv = wv[j*3+1]*yc + bv[j];
    float zz = chv + cvv;
    zz = (zz - mm[j])*rsqrtf(vv[j]+EPSF)*g[j] + bb[j];
    z[(long)row*512 + j] = gelu_f(zz);
  }
}

extern "C" void kernel_launch(void* const* d_in, const int* in_sizes, int n_in,
                              void* d_out, int out_size, void* d_ws, size_t ws_size,
                              hipStream_t stream)
{
  const float* x_in  = (const float*)d_in[0];
  const float* ln1_g = (const float*)d_in[1];
  const float* ln1_b = (const float*)d_in[2];
  const float* w_qkv = (const float*)d_in[3];
  const float* w_out = (const float*)d_in[4];
  const float* b_out = (const float*)d_in[5];
  const float* ln2_g = (const float*)d_in[6];
  const float* ln2_b = (const float*)d_in[7];
  const float* w_fc1 = (const float*)d_in[8];
  const float* b_fc1 = (const float*)d_in[9];
  const float* wh    = (const float*)d_in[10];
  const float* bh    = (const float*)d_in[11];
  const float* wv    = (const float*)d_in[12];
  const float* bv    = (const float*)d_in[13];
  const float* bn_g  = (const float*)d_in[14];
  const float* bn_b  = (const float*)d_in[15];
  const float* bn_m  = (const float*)d_in[16];
  const float* bn_v  = (const float*)d_in[17];
  const float* w_fc2 = (const float*)d_in[18];
  const float* b_fc2 = (const float*)d_in[19];
  const float* ls_w1 = (const float*)d_in[20];
  const float* ls_w2 = (const float*)d_in[21];

  // ws layout (floats): total 10,506,240 = 42.0 MB
  float* ws = (float*)d_ws;
  float* xbuf = ws;                    // 2,097,152  [B*N][256]
  float* hbuf = xbuf + 2097152;        // 2,097,152  [B*N][256]
  float* big  = hbuf + 2097152;        // 6,291,456  qkv [B*N][768]; MLP overlay
  float* qkv  = big;
  float* ybuf = big;                   // [4096][512] per MLP chunk
  float* zbuf = big + 2097152;         // [4096][512] per MLP chunk
  float* partial = big + 6291456;      // 16,384
  float* cm   = partial + 16384;       // 2,048
  float* gate = cm + 2048;             // 2,048

  copy4_k<<<2048,256,0,stream>>>(x_in, xbuf);

  for (int l=0;l<2;l++){
    const float* wqkv_l = w_qkv + (long)l*256*768;
    const float* wout_l = w_out + (long)l*256*256;
    const float* bout_l = b_out + l*256;
    const float* wfc1_l = w_fc1 + (long)l*256*512;
    const float* bfc1_l = b_fc1 + l*512;
    const float* wfc2_l = w_fc2 + (long)l*512*256;
    const float* bfc2_l = b_fc2 + l*256;
    const float* lw1_l  = ls_w1 + (long)l*256*64;
    const float* lw2_l  = ls_w2 + (long)l*64*256;

    // --- MHSA ---
    ln_k<<<8192,256,0,stream>>>(xbuf, ln1_g + l*256, ln1_b + l*256, hbuf);
    gemm_k<128,128,8,8,8,0,false,false><<<dim3(6,64),256,0,stream>>>(
        hbuf,256, wqkv_l,768, qkv,768, nullptr, nullptr, 256);
    attn_k<<<dim3(16,32),256,0,stream>>>(qkv, hbuf);   // O overwrites LN buffer
    gemm_k<128,128,8,8,8,0,true,true><<<dim3(2,64),256,0,stream>>>(
        hbuf,256, wout_l,256, xbuf,256, bout_l, xbuf, 256);

    semean1_k<<<64,256,0,stream>>>(xbuf, partial);
    semean2_k<<<8,256,0,stream>>>(partial, cm);
    segate_k<<<8,256,0,stream>>>(cm, lw1_l, lw2_l, gate);
    seapply_k<<<2048,256,0,stream>>>(xbuf, gate);

    // --- MLP (2 chunks of 4096 rows; chunk boundary = batch boundary) ---
    ln_k<<<8192,256,0,stream>>>(xbuf, ln2_g + l*256, ln2_b + l*256, hbuf);
    for (int c=0;c<2;c++){
      const long r0 = (long)c*4096;
      gemm_k<128,128,8,8,8,1,false,true><<<dim3(4,32),256,0,stream>>>(
          hbuf + r0*256,256, wfc1_l,512, ybuf,512, bfc1_l, nullptr, 256);
      conv_k<<<4096,256,0,stream>>>(ybuf, zbuf, wh + (long)l*512*3, bh + l*512,
          wv + (long)l*512*3, bv + l*512, bn_g + l*512, bn_b + l*512,
          bn_m + l*512, bn_v + l*512);
      gemm_k<128,128,8,8,8,0,true,true><<<dim3(2,32),256,0,stream>>>(
          zbuf,512, wfc2_l,256, xbuf + r0*256,256, bfc2_l, xbuf + r0*256, 512);
    }

    semean1_k<<<64,256,0,stream>>>(xbuf, partial);
    semean2_k<<<8,256,0,stream>>>(partial, cm);
    segate_k<<<8,256,0,stream>>>(cm, lw1_l, lw2_l, gate);
    seapply_k<<<2048,256,0,stream>>>(xbuf, gate);
  }

  copy4_k<<<2048,256,0,stream>>>(xbuf, (float*)d_out);   // fp32 output
}

// Round 7
// 666.664 us; speedup vs baseline: 1.9379x; 1.9379x over previous
//
#include <hip/hip_runtime.h>
#include <hip/hip_bf16.h>
#include <math.h>

#define EPSF 1e-5f

typedef short bf16x8 __attribute__((ext_vector_type(8)));
typedef float f32x4  __attribute__((ext_vector_type(4)));

__device__ __forceinline__ float gelu_f(float z){
  return 0.5f*z*(1.0f + erff(z*0.70710678118654752f));
}

// round-to-nearest-even fp32 -> bf16 bits
__device__ __forceinline__ unsigned short f2bf(float f){
  unsigned u = __float_as_uint(f);
  u += 0x7FFFu + ((u >> 16) & 1u);
  return (unsigned short)(u >> 16);
}

// ---------------- copy ----------------
__global__ void copy4_k(const float* __restrict__ s, float* __restrict__ d){
  long i = (long)blockIdx.x*blockDim.x + threadIdx.x;
  reinterpret_cast<float4*>(d)[i] = reinterpret_cast<const float4*>(s)[i];
}

// ---------------- fp32 -> bf16 (4/thread) ----------------
__global__ void f2b_k(const float* __restrict__ x, unsigned short* __restrict__ o){
  long i = (long)blockIdx.x*256 + threadIdx.x;
  float4 v = reinterpret_cast<const float4*>(x)[i];
  ushort4 u;
  u.x = f2bf(v.x); u.y = f2bf(v.y); u.z = f2bf(v.z); u.w = f2bf(v.w);
  reinterpret_cast<ushort4*>(o)[i] = u;
}

// ---------------- transpose + cast: in fp32 [K][N] -> out bf16 [N][K] ----------------
__global__ void tcast_k(const float* __restrict__ in, unsigned short* __restrict__ out,
                        int K, int N){
  int idx = blockIdx.x*256 + threadIdx.x;
  if (idx >= K*N) return;
  int n = idx / K, k = idx % K;
  out[idx] = f2bf(in[(long)k*N + n]);
}

// ---------------- LayerNorm -> bf16 (one row of 256 per block) ----------------
__global__ void ln_bf_k(const float* __restrict__ x, const float* __restrict__ g,
                        const float* __restrict__ b, unsigned short* __restrict__ out){
  const int row = blockIdx.x;
  const int t = threadIdx.x;
  float v = x[(long)row*256 + t];
  float s = v, s2 = v*v;
  for (int o=32;o>0;o>>=1){ s += __shfl_down(s,o); s2 += __shfl_down(s2,o); }
  __shared__ float ls[4], ls2[4];
  const int w = t>>6, lane = t&63;
  if (lane==0){ ls[w]=s; ls2[w]=s2; }
  __syncthreads();
  if (t==0){
    float a  = ls[0]+ls[1]+ls[2]+ls[3];
    float a2 = ls2[0]+ls2[1]+ls2[2]+ls2[3];
    float mu = a*(1.f/256.f);
    float var = a2*(1.f/256.f) - mu*mu;
    ls[0]=mu; ls2[0]=rsqrtf(var+EPSF);
  }
  __syncthreads();
  out[(long)row*256+t] = f2bf((v-ls[0])*ls2[0]*g[t] + b[t]);
}

// ---------------- bf16 MFMA GEMM: C = act(A@Bt^T + bias + res) ----------------
// A: [M][K] bf16 row-major. Bt: [N][K] bf16 row-major. C: [M][N] fp32 (ldc=N).
// grid (N/128, M/128), block 256 (4 waves, each 64x64).
template<int ACT, bool RES, bool BIAS>
__global__ __launch_bounds__(256,2)
void gmm_k(const unsigned short* __restrict__ A,
           const unsigned short* __restrict__ Bt,
           float* __restrict__ C, int ldc,
           const float* __restrict__ bias,
           const float* __restrict__ res,
           int K)
{
  __shared__ unsigned short As[128*64];
  __shared__ unsigned short Bs[128*64];
  const int tid  = threadIdx.x;
  const int wave = tid>>6, lane = tid&63;
  const int wm = (wave>>1)*64, wn = (wave&1)*64;
  const int m0 = blockIdx.y*128, n0 = blockIdx.x*128;
  const int lrow = lane&15, quad = lane>>4;

  f32x4 acc[4][4];
  #pragma unroll
  for (int i=0;i<4;i++)
    #pragma unroll
    for (int j=0;j<4;j++)
      #pragma unroll
      for (int r=0;r<4;r++) acc[i][j][r]=0.f;

  for (int k0=0;k0<K;k0+=64){
    __syncthreads();
    #pragma unroll
    for (int it=0; it<4; it++){
      int idx = tid + it*256;
      int row = idx>>3, c = idx&7;
      int g = c ^ (row&7);                  // XOR swizzle: 2-way max on rd/wr
      *reinterpret_cast<uint4*>(&As[row*64 + g*8]) =
        *reinterpret_cast<const uint4*>(A + (long)(m0+row)*K + k0 + c*8);
      *reinterpret_cast<uint4*>(&Bs[row*64 + g*8]) =
        *reinterpret_cast<const uint4*>(Bt + (long)(n0+row)*K + k0 + c*8);
    }
    __syncthreads();
    #pragma unroll
    for (int s=0;s<2;s++){
      bf16x8 a[4], b[4];
      const int ck = s*4 + quad;            // 8-short chunk index within BK=64
      #pragma unroll
      for (int i=0;i<4;i++){
        int row = wm + 16*i + lrow;
        a[i] = *reinterpret_cast<const bf16x8*>(&As[row*64 + (ck ^ (row&7))*8]);
      }
      #pragma unroll
      for (int j=0;j<4;j++){
        int n = wn + 16*j + lrow;
        b[j] = *reinterpret_cast<const bf16x8*>(&Bs[n*64 + (ck ^ (n&7))*8]);
      }
      #pragma unroll
      for (int i=0;i<4;i++)
        #pragma unroll
        for (int j=0;j<4;j++)
          acc[i][j] = __builtin_amdgcn_mfma_f32_16x16x32_bf16(a[i], b[j], acc[i][j], 0,0,0);
    }
  }

  // epilogue: C/D layout col=lane&15, row=quad*4+reg
  #pragma unroll
  for (int i=0;i<4;i++){
    #pragma unroll
    for (int j=0;j<4;j++){
      const int col = n0 + wn + 16*j + lrow;
      const float bv = BIAS ? bias[col] : 0.f;
      #pragma unroll
      for (int r=0;r<4;r++){
        const int row = m0 + wm + 16*i + quad*4 + r;
        const long off = (long)row*ldc + col;
        float v = acc[i][j][r] + bv;
        if (RES) v += res[off];
        if (ACT==1) v = gelu_f(v);
        C[off] = v;
      }
    }
  }
}

// ---------------- fused flash attention (fp32, 52 KB LDS) ----------------
__global__ __launch_bounds__(256)
void attn_k(const float* __restrict__ qkv, float* __restrict__ o){
  const int q0 = blockIdx.x * 64;
  const int bh = blockIdx.y;
  const int b = bh >> 2, h = bh & 3;
  const int tid = threadIdx.x;
  const int tcol = tid & 15;
  const int trow = tid >> 4;

  __shared__ float Qs[64][68];
  __shared__ float Ks[64][68];   // doubles as P after S-compute
  __shared__ float Vs[64][68];

  const long rowbase = (long)b*1024;
  for (int f = tid; f < 1024; f += 256){
    int r = f >> 4, d4 = (f & 15) << 2;
    *reinterpret_cast<float4*>(&Qs[r][d4]) =
      *reinterpret_cast<const float4*>(qkv + (rowbase + q0 + r)*768 + h*64 + d4);
  }

  float m_i[4], l_i[4], acc[4][4];
  #pragma unroll
  for (int r=0;r<4;r++){
    m_i[r] = -1e30f; l_i[r] = 0.f;
    #pragma unroll
    for (int c=0;c<4;c++) acc[r][c] = 0.f;
  }

  for (int k0 = 0; k0 < 1024; k0 += 64){
    __syncthreads();
    for (int f = tid; f < 1024; f += 256){
      int r = f >> 4, d4 = (f & 15) << 2;
      const float* src = qkv + (rowbase + k0 + r)*768 + h*64 + d4;
      *reinterpret_cast<float4*>(&Ks[r][d4]) = *reinterpret_cast<const float4*>(src + 256);
      *reinterpret_cast<float4*>(&Vs[r][d4]) = *reinterpret_cast<const float4*>(src + 512);
    }
    __syncthreads();

    float s[4][4];
    #pragma unroll
    for (int r=0;r<4;r++)
      #pragma unroll
      for (int j=0;j<4;j++) s[r][j] = 0.f;

    #pragma unroll
    for (int d4=0; d4<64; d4+=4){
      float4 q4[4], k4[4];
      #pragma unroll
      for (int rr=0;rr<4;rr++)
        q4[rr] = *reinterpret_cast<const float4*>(&Qs[4*trow+rr][d4]);
      #pragma unroll
      for (int jj=0;jj<4;jj++)
        k4[jj] = *reinterpret_cast<const float4*>(&Ks[tcol+16*jj][d4]);
      #pragma unroll
      for (int rr=0;rr<4;rr++)
        #pragma unroll
        for (int jj=0;jj<4;jj++){
          s[rr][jj] = fmaf(q4[rr].x, k4[jj].x, s[rr][jj]);
          s[rr][jj] = fmaf(q4[rr].y, k4[jj].y, s[rr][jj]);
          s[rr][jj] = fmaf(q4[rr].z, k4[jj].z, s[rr][jj]);
          s[rr][jj] = fmaf(q4[rr].w, k4[jj].w, s[rr][jj]);
        }
    }

    float pl[4][4];
    #pragma unroll
    for (int rr=0;rr<4;rr++){
      float mx = -1e30f;
      #pragma unroll
      for (int jj=0;jj<4;jj++){ s[rr][jj] *= 0.125f; mx = fmaxf(mx, s[rr][jj]); }
      #pragma unroll
      for (int off=8; off>0; off>>=1) mx = fmaxf(mx, __shfl_xor(mx, off));
      const float mnew = fmaxf(m_i[rr], mx);
      const float alpha = __expf(m_i[rr] - mnew);
      m_i[rr] = mnew;
      float rs = 0.f;
      #pragma unroll
      for (int jj=0;jj<4;jj++){
        float p = __expf(s[rr][jj] - mnew);
        pl[rr][jj] = p; rs += p;
      }
      #pragma unroll
      for (int off=8; off>0; off>>=1) rs += __shfl_xor(rs, off);
      l_i[rr] = l_i[rr]*alpha + rs;
      #pragma unroll
      for (int c=0;c<4;c++) acc[rr][c] *= alpha;
    }

    __syncthreads();
    #pragma unroll
    for (int rr=0;rr<4;rr++)
      #pragma unroll
      for (int jj=0;jj<4;jj++)
        Ks[4*trow+rr][tcol+16*jj] = pl[rr][jj];

    #pragma unroll
    for (int j4=0;j4<64;j4+=4){
      float4 p4[4], v4[4];
      #pragma unroll
      for (int rr=0;rr<4;rr++)
        p4[rr] = *reinterpret_cast<const float4*>(&Ks[4*trow+rr][j4]);
      #pragma unroll
      for (int jj=0;jj<4;jj++)
        v4[jj] = *reinterpret_cast<const float4*>(&Vs[j4+jj][4*tcol]);
      #pragma unroll
      for (int rr=0;rr<4;rr++){
        acc[rr][0] = fmaf(p4[rr].x, v4[0].x, acc[rr][0]);
        acc[rr][1] = fmaf(p4[rr].x, v4[0].y, acc[rr][1]);
        acc[rr][2] = fmaf(p4[rr].x, v4[0].z, acc[rr][2]);
        acc[rr][3] = fmaf(p4[rr].x, v4[0].w, acc[rr][3]);
        acc[rr][0] = fmaf(p4[rr].y, v4[1].x, acc[rr][0]);
        acc[rr][1] = fmaf(p4[rr].y, v4[1].y, acc[rr][1]);
        acc[rr][2] = fmaf(p4[rr].y, v4[1].z, acc[rr][2]);
        acc[rr][3] = fmaf(p4[rr].y, v4[1].w, acc[rr][3]);
        acc[rr][0] = fmaf(p4[rr].z, v4[2].x, acc[rr][0]);
        acc[rr][1] = fmaf(p4[rr].z, v4[2].y, acc[rr][1]);
        acc[rr][2] = fmaf(p4[rr].z, v4[2].z, acc[rr][2]);
        acc[rr][3] = fmaf(p4[rr].z, v4[2].w, acc[rr][3]);
        acc[rr][0] = fmaf(p4[rr].w, v4[3].x, acc[rr][0]);
        acc[rr][1] = fmaf(p4[rr].w, v4[3].y, acc[rr][1]);
        acc[rr][2] = fmaf(p4[rr].w, v4[3].z, acc[rr][2]);
        acc[rr][3] = fmaf(p4[rr].w, v4[3].w, acc[rr][3]);
      }
    }
  }

  #pragma unroll
  for (int rr=0;rr<4;rr++){
    const float inv = 1.f / l_i[rr];
    float4 v;
    v.x = acc[rr][0]*inv; v.y = acc[rr][1]*inv;
    v.z = acc[rr][2]*inv; v.w = acc[rr][3]*inv;
    *reinterpret_cast<float4*>(o + (rowbase + q0 + 4*trow + rr)*256 + h*64 + 4*tcol) = v;
  }
}

// ---------------- SE gate helpers ----------------
__global__ void semean1_k(const float* __restrict__ x, float* __restrict__ part){
  const int blk = blockIdx.x; const int b = blk>>3, sl = blk&7;
  const int t = threadIdx.x;
  const float* p = x + ((long)b*1024 + sl*128)*256 + t;
  float s=0.f;
  for (int i=0;i<128;i++) s += p[(long)i*256];
  part[(long)blk*256 + t] = s;
}

__global__ void semean2_k(const float* __restrict__ part, float* __restrict__ cm){
  const int b = blockIdx.x, t = threadIdx.x;
  float s=0.f;
  for (int i=0;i<8;i++) s += part[(long)(b*8+i)*256 + t];
  cm[b*256+t] = s*(1.f/1024.f);
}

__global__ void segate_k(const float* __restrict__ cm, const float* __restrict__ w1,
                         const float* __restrict__ w2, float* __restrict__ gate){
  const int b = blockIdx.x, t = threadIdx.x;
  __shared__ float sc[256], sh[64];
  sc[t] = cm[b*256+t];
  __syncthreads();
  if (t < 64){
    float s=0.f;
    for (int k=0;k<256;k++) s += sc[k]*w1[k*64+t];
    sh[t] = fmaxf(s, 0.f);
  }
  __syncthreads();
  float s=0.f;
  for (int k=0;k<64;k++) s += sh[k]*w2[k*256+t];
  gate[b*256+t] = 1.f/(1.f+__expf(-s));
}

__global__ void seapply_k(float* __restrict__ x, const float* __restrict__ gate){
  long o4 = ((long)blockIdx.x*256 + threadIdx.x)*4;
  float4 v = *reinterpret_cast<float4*>(x+o4);
  float4 g = *reinterpret_cast<const float4*>(gate + (((o4>>18)<<8) | (o4 & 255)));
  v.x*=g.x; v.y*=g.y; v.z*=g.z; v.w*=g.w;
  *reinterpret_cast<float4*>(x+o4) = v;
}

// ---------------- depthwise conv + BN + GELU -> bf16 ----------------
__global__ void conv_bf_k(const float* __restrict__ y, unsigned short* __restrict__ z,
   const float* __restrict__ wh, const float* __restrict__ bh,
   const float* __restrict__ wv, const float* __restrict__ bv,
   const float* __restrict__ g, const float* __restrict__ bb,
   const float* __restrict__ mm, const float* __restrict__ vv)
{
  const int row = blockIdx.x;
  const int n = row & 1023;
  const float* yr = y + (long)row*512;
  for (int j=threadIdx.x; j<512; j+=256){
    float yc = yr[j];
    float ym = (n>0)   ? yr[j-512] : 0.f;
    float yp = (n<1023)? yr[j+512] : 0.f;
    float chv = wh[j*3+0]*ym + wh[j*3+1]*yc + wh[j*3+2]*yp + bh[j];
    float cvv = wv[j*3+1]*yc + bv[j];
    float zz = chv + cvv;
    zz = (zz - mm[j])*rsqrtf(vv[j]+EPSF)*g[j] + bb[j];
    z[(long)row*512 + j] = f2bf(gelu_f(zz));
  }
}

extern "C" void kernel_launch(void* const* d_in, const int* in_sizes, int n_in,
                              void* d_out, int out_size, void* d_ws, size_t ws_size,
                              hipStream_t stream)
{
  const float* x_in  = (const float*)d_in[0];
  const float* ln1_g = (const float*)d_in[1];
  const float* ln1_b = (const float*)d_in[2];
  const float* w_qkv = (const float*)d_in[3];
  const float* w_out = (const float*)d_in[4];
  const float* b_out = (const float*)d_in[5];
  const float* ln2_g = (const float*)d_in[6];
  const float* ln2_b = (const float*)d_in[7];
  const float* w_fc1 = (const float*)d_in[8];
  const float* b_fc1 = (const float*)d_in[9];
  const float* wh    = (const float*)d_in[10];
  const float* bh    = (const float*)d_in[11];
  const float* wv    = (const float*)d_in[12];
  const float* bv    = (const float*)d_in[13];
  const float* bn_g  = (const float*)d_in[14];
  const float* bn_b  = (const float*)d_in[15];
  const float* bn_m  = (const float*)d_in[16];
  const float* bn_v  = (const float*)d_in[17];
  const float* w_fc2 = (const float*)d_in[18];
  const float* b_fc2 = (const float*)d_in[19];
  const float* ls_w1 = (const float*)d_in[20];
  const float* ls_w2 = (const float*)d_in[21];

  // ws layout (floats), total ~18.4M floats = 73.5 MB
  float* ws   = (float*)d_ws;
  float* xbuf = ws;                      // 2,097,152
  float* qkv  = xbuf + 2097152;          // 6,291,456
  float* obuf = qkv  + 6291456;          // 2,097,152 (attn out fp32)
  float* ybuf = obuf + 2097152;          // 4,194,304 (fc1 out fp32)
  float* partial = ybuf + 4194304;       // 16,384
  float* cm   = partial + 16384;         // 2,048
  float* gate = cm + 2048;               // 2,048
  unsigned short* habf = (unsigned short*)(gate + 2048);   // 2,097,152 sh (1,048,576 fl)
  unsigned short* zbf  = habf + 2097152;                   // 4,194,304 sh
  unsigned short* wqkv_t = zbf + 4194304;                  // 2*768*256
  unsigned short* wout_t = wqkv_t + 2*768*256;             // 2*256*256
  unsigned short* wfc1_t = wout_t + 2*256*256;             // 2*512*256
  unsigned short* wfc2_t = wfc1_t + 2*512*256;             // 2*256*512

  copy4_k<<<2048,256,0,stream>>>(x_in, xbuf);

  // weight transpose+cast (once per launch)
  for (int l=0;l<2;l++){
    tcast_k<<<(768*256+255)/256,256,0,stream>>>(w_qkv + (long)l*256*768, wqkv_t + (long)l*768*256, 256, 768);
    tcast_k<<<(256*256+255)/256,256,0,stream>>>(w_out + (long)l*256*256, wout_t + (long)l*256*256, 256, 256);
    tcast_k<<<(512*256+255)/256,256,0,stream>>>(w_fc1 + (long)l*256*512, wfc1_t + (long)l*512*256, 256, 512);
    tcast_k<<<(256*512+255)/256,256,0,stream>>>(w_fc2 + (long)l*512*256, wfc2_t + (long)l*256*512, 512, 256);
  }

  for (int l=0;l<2;l++){
    const float* bout_l = b_out + l*256;
    const float* bfc1_l = b_fc1 + l*512;
    const float* bfc2_l = b_fc2 + l*256;
    const float* lw1_l  = ls_w1 + (long)l*256*64;
    const float* lw2_l  = ls_w2 + (long)l*64*256;

    // --- MHSA ---
    ln_bf_k<<<8192,256,0,stream>>>(xbuf, ln1_g + l*256, ln1_b + l*256, habf);
    gmm_k<0,false,false><<<dim3(6,64),256,0,stream>>>(
        habf, wqkv_t + (long)l*768*256, qkv, 768, nullptr, nullptr, 256);
    attn_k<<<dim3(16,32),256,0,stream>>>(qkv, obuf);
    f2b_k<<<2048,256,0,stream>>>(obuf, habf);
    gmm_k<0,true,true><<<dim3(2,64),256,0,stream>>>(
        habf, wout_t + (long)l*256*256, xbuf, 256, bout_l, xbuf, 256);

    semean1_k<<<64,256,0,stream>>>(xbuf, partial);
    semean2_k<<<8,256,0,stream>>>(partial, cm);
    segate_k<<<8,256,0,stream>>>(cm, lw1_l, lw2_l, gate);
    seapply_k<<<2048,256,0,stream>>>(xbuf, gate);

    // --- MLP (full 8192 rows) ---
    ln_bf_k<<<8192,256,0,stream>>>(xbuf, ln2_g + l*256, ln2_b + l*256, habf);
    gmm_k<1,false,true><<<dim3(4,64),256,0,stream>>>(
        habf, wfc1_t + (long)l*512*256, ybuf, 512, bfc1_l, nullptr, 256);
    conv_bf_k<<<8192,256,0,stream>>>(ybuf, zbf, wh + (long)l*512*3, bh + l*512,
        wv + (long)l*512*3, bv + l*512, bn_g + l*512, bn_b + l*512,
        bn_m + l*512, bn_v + l*512);
    gmm_k<0,true,true><<<dim3(2,64),256,0,stream>>>(
        zbf, wfc2_t + (long)l*256*512, xbuf, 256, bfc2_l, xbuf, 512);

    semean1_k<<<64,256,0,stream>>>(xbuf, partial);
    semean2_k<<<8,256,0,stream>>>(partial, cm);
    segate_k<<<8,256,0,stream>>>(cm, lw1_l, lw2_l, gate);
    seapply_k<<<2048,256,0,stream>>>(xbuf, gate);
  }

  copy4_k<<<2048,256,0,stream>>>(xbuf, (float*)d_out);
}

// Round 8
// 452.065 us; speedup vs baseline: 2.8578x; 1.4747x over previous
//
#include <hip/hip_runtime.h>
#include <hip/hip_bf16.h>
#include <math.h>

#define EPSF 1e-5f

typedef short bf16x8 __attribute__((ext_vector_type(8)));
typedef float f32x4  __attribute__((ext_vector_type(4)));

__device__ __forceinline__ float gelu_f(float z){
  return 0.5f*z*(1.0f + erff(z*0.70710678118654752f));
}

__device__ __forceinline__ unsigned short f2bf(float f){
  unsigned u = __float_as_uint(f);
  u += 0x7FFFu + ((u >> 16) & 1u);
  return (unsigned short)(u >> 16);
}

// ---------------- copy ----------------
__global__ void copy4_k(const float* __restrict__ s, float* __restrict__ d){
  long i = (long)blockIdx.x*blockDim.x + threadIdx.x;
  reinterpret_cast<float4*>(d)[i] = reinterpret_cast<const float4*>(s)[i];
}

// ---------------- transpose + cast: in fp32 [K][N] -> out bf16 [N][K] ----------------
__global__ void tcast_k(const float* __restrict__ in, unsigned short* __restrict__ out,
                        int K, int N){
  int idx = blockIdx.x*256 + threadIdx.x;
  if (idx >= K*N) return;
  int n = idx / K, k = idx % K;
  out[idx] = f2bf(in[(long)k*N + n]);
}

// ---------------- LayerNorm -> bf16 ----------------
__global__ void ln_bf_k(const float* __restrict__ x, const float* __restrict__ g,
                        const float* __restrict__ b, unsigned short* __restrict__ out){
  const int row = blockIdx.x;
  const int t = threadIdx.x;
  float v = x[(long)row*256 + t];
  float s = v, s2 = v*v;
  for (int o=32;o>0;o>>=1){ s += __shfl_down(s,o); s2 += __shfl_down(s2,o); }
  __shared__ float ls[4], ls2[4];
  const int w = t>>6, lane = t&63;
  if (lane==0){ ls[w]=s; ls2[w]=s2; }
  __syncthreads();
  if (t==0){
    float a  = ls[0]+ls[1]+ls[2]+ls[3];
    float a2 = ls2[0]+ls2[1]+ls2[2]+ls2[3];
    float mu = a*(1.f/256.f);
    float var = a2*(1.f/256.f) - mu*mu;
    ls[0]=mu; ls2[0]=rsqrtf(var+EPSF);
  }
  __syncthreads();
  out[(long)row*256+t] = f2bf((v-ls[0])*ls2[0]*g[t] + b[t]);
}

// ---------------- bf16 MFMA GEMM: C = act(A@Bt^T + bias + res) ----------------
// A: [M][K] bf16. Bt: [N][K] bf16. C: fp32 or bf16 (OBF). grid (N/128, M/128), 256 thr.
template<int ACT, bool RES, bool BIAS, bool OBF>
__global__ __launch_bounds__(256,2)
void gmm_k(const unsigned short* __restrict__ A,
           const unsigned short* __restrict__ Bt,
           void* __restrict__ Cv, int ldc,
           const float* __restrict__ bias,
           const float* __restrict__ res,
           int K)
{
  __shared__ unsigned short As[128*64];
  __shared__ unsigned short Bs[128*64];
  float* C = (float*)Cv;
  unsigned short* Cb = (unsigned short*)Cv;
  const int tid  = threadIdx.x;
  const int wave = tid>>6, lane = tid&63;
  const int wm = (wave>>1)*64, wn = (wave&1)*64;
  const int m0 = blockIdx.y*128, n0 = blockIdx.x*128;
  const int lrow = lane&15, quad = lane>>4;

  f32x4 acc[4][4];
  #pragma unroll
  for (int i=0;i<4;i++)
    #pragma unroll
    for (int j=0;j<4;j++)
      #pragma unroll
      for (int r=0;r<4;r++) acc[i][j][r]=0.f;

  for (int k0=0;k0<K;k0+=64){
    __syncthreads();
    #pragma unroll
    for (int it=0; it<4; it++){
      int idx = tid + it*256;
      int row = idx>>3, c = idx&7;
      int g = c ^ (row&7);
      *reinterpret_cast<uint4*>(&As[row*64 + g*8]) =
        *reinterpret_cast<const uint4*>(A + (long)(m0+row)*K + k0 + c*8);
      *reinterpret_cast<uint4*>(&Bs[row*64 + g*8]) =
        *reinterpret_cast<const uint4*>(Bt + (long)(n0+row)*K + k0 + c*8);
    }
    __syncthreads();
    #pragma unroll
    for (int s=0;s<2;s++){
      bf16x8 a[4], b[4];
      const int ck = s*4 + quad;
      #pragma unroll
      for (int i=0;i<4;i++){
        int row = wm + 16*i + lrow;
        a[i] = *reinterpret_cast<const bf16x8*>(&As[row*64 + (ck ^ (row&7))*8]);
      }
      #pragma unroll
      for (int j=0;j<4;j++){
        int n = wn + 16*j + lrow;
        b[j] = *reinterpret_cast<const bf16x8*>(&Bs[n*64 + (ck ^ (n&7))*8]);
      }
      #pragma unroll
      for (int i=0;i<4;i++)
        #pragma unroll
        for (int j=0;j<4;j++)
          acc[i][j] = __builtin_amdgcn_mfma_f32_16x16x32_bf16(a[i], b[j], acc[i][j], 0,0,0);
    }
  }

  #pragma unroll
  for (int i=0;i<4;i++){
    #pragma unroll
    for (int j=0;j<4;j++){
      const int col = n0 + wn + 16*j + lrow;
      const float bv = BIAS ? bias[col] : 0.f;
      #pragma unroll
      for (int r=0;r<4;r++){
        const int row = m0 + wm + 16*i + quad*4 + r;
        const long off = (long)row*ldc + col;
        float v = acc[i][j][r] + bv;
        if (RES) v += res[off];
        if (ACT==1) v = gelu_f(v);
        if (OBF) Cb[off] = f2bf(v); else C[off] = v;
      }
    }
  }
}

// ---------------- MFMA flash attention (bf16 in/out, fp32 softmax state) ----------------
// qkvb: [B*N][768] bf16 (q 0..255, k 256..511, v 512..767; col=h*64+d)
// o: [B*N][256] bf16 merged. grid (16 q-tiles, 32 bh), block 256 (4 waves x 16 q-rows).
__global__ __launch_bounds__(256)
void attn_k(const unsigned short* __restrict__ qkvb, unsigned short* __restrict__ o){
  const int q0 = blockIdx.x * 64;
  const int bh = blockIdx.y;
  const int b = bh >> 2, h = bh & 3;
  const int tid = threadIdx.x;
  const int wv = tid >> 6;
  const int lane = tid & 63;
  const int l15 = lane & 15, quad = lane >> 4;

  __shared__ unsigned short Qs[64*64];   // [qrow][d], granule^ (row&7)
  __shared__ unsigned short Ks[64*64];   // [key][d],  granule^ (key&7)
  __shared__ unsigned short Vt[64*64];   // [d][key],  granule^ ((d>>3)&7)
  __shared__ unsigned short Ps[64*64];   // [qrow][key], granule^ ((row>>2)&7)

  const long rowbase = (long)b*1024;

  for (int f = tid; f < 512; f += 256){
    int row = f >> 3, g = f & 7;
    int p = g ^ (row & 7);
    *reinterpret_cast<uint4*>(&Qs[row*64 + p*8]) =
      *reinterpret_cast<const uint4*>(qkvb + (rowbase + q0 + row)*768 + h*64 + g*8);
  }

  float m_i[4], l_i[4];
  f32x4 acc[4];
  #pragma unroll
  for (int r=0;r<4;r++){ m_i[r] = -1e30f; l_i[r] = 0.f; }
  #pragma unroll
  for (int j=0;j<4;j++)
    #pragma unroll
    for (int r=0;r<4;r++) acc[j][r] = 0.f;

  for (int k0 = 0; k0 < 1024; k0 += 64){
    __syncthreads();   // prev-iter Ks/Vt reads done (iter0: Q visible)
    for (int f = tid; f < 512; f += 256){
      int row = f >> 3, g = f & 7;
      const unsigned short* src = qkvb + (rowbase + k0 + row)*768 + h*64 + g*8;
      int pk = g ^ (row & 7);
      *reinterpret_cast<uint4*>(&Ks[row*64 + pk*8]) =
        *reinterpret_cast<const uint4*>(src + 256);
      uint4 vvv = *reinterpret_cast<const uint4*>(src + 512);
      const unsigned short* vs = reinterpret_cast<const unsigned short*>(&vvv);
      #pragma unroll
      for (int i=0;i<8;i++){
        int d = g*8 + i;
        int pv = (row >> 3) ^ ((d >> 3) & 7);
        Vt[d*64 + pv*8 + (row & 7)] = vs[i];
      }
    }
    __syncthreads();

    // S = Q K^T (wave's 16 q-rows x 64 keys)
    f32x4 s[4];
    #pragma unroll
    for (int j=0;j<4;j++)
      #pragma unroll
      for (int r=0;r<4;r++) s[j][r] = 0.f;

    #pragma unroll
    for (int half=0; half<2; half++){
      const int ck = half*4 + quad;
      const int qrow = 16*wv + l15;
      bf16x8 a = *reinterpret_cast<const bf16x8*>(&Qs[qrow*64 + (ck ^ (qrow&7))*8]);
      #pragma unroll
      for (int j=0;j<4;j++){
        int krow = 16*j + l15;
        bf16x8 bb = *reinterpret_cast<const bf16x8*>(&Ks[krow*64 + (ck ^ (krow&7))*8]);
        s[j] = __builtin_amdgcn_mfma_f32_16x16x32_bf16(a, bb, s[j], 0,0,0);
      }
    }

    // online softmax: C/D layout row = quad*4+r (q), col = l15+16j (key)
    #pragma unroll
    for (int r=0;r<4;r++){
      float mx = -1e30f;
      #pragma unroll
      for (int j=0;j<4;j++){ s[j][r] *= 0.125f; mx = fmaxf(mx, s[j][r]); }
      #pragma unroll
      for (int off=8; off>0; off>>=1) mx = fmaxf(mx, __shfl_xor(mx, off));
      const float mnew = fmaxf(m_i[r], mx);
      const float alpha = __expf(m_i[r] - mnew);
      m_i[r] = mnew;
      float rs = 0.f;
      #pragma unroll
      for (int j=0;j<4;j++){ float p = __expf(s[j][r]-mnew); s[j][r] = p; rs += p; }
      #pragma unroll
      for (int off=8; off>0; off>>=1) rs += __shfl_xor(rs, off);
      l_i[r] = l_i[r]*alpha + rs;
      #pragma unroll
      for (int j=0;j<4;j++) acc[j][r] *= alpha;
    }

    // P -> LDS (wave-private rows; in-wave DS ordering suffices)
    #pragma unroll
    for (int j=0;j<4;j++)
      #pragma unroll
      for (int r=0;r<4;r++){
        int rowq = 16*wv + quad*4 + r;
        int key = l15 + 16*j;
        int pp = (key>>3) ^ ((rowq>>2)&7);
        Ps[rowq*64 + pp*8 + (key&7)] = f2bf(s[j][r]);
      }

    // O += P V
    #pragma unroll
    for (int half=0; half<2; half++){
      const int ck = half*4 + quad;
      const int prow = 16*wv + l15;
      bf16x8 a = *reinterpret_cast<const bf16x8*>(&Ps[prow*64 + (ck ^ ((prow>>2)&7))*8]);
      #pragma unroll
      for (int jj=0;jj<4;jj++){
        int drow = 16*jj + l15;
        bf16x8 bb = *reinterpret_cast<const bf16x8*>(&Vt[drow*64 + (ck ^ ((drow>>3)&7))*8]);
        acc[jj] = __builtin_amdgcn_mfma_f32_16x16x32_bf16(a, bb, acc[jj], 0,0,0);
      }
    }
  }

  #pragma unroll
  for (int r=0;r<4;r++){
    const float inv = 1.f / l_i[r];
    const long rowq = rowbase + q0 + 16*wv + quad*4 + r;
    #pragma unroll
    for (int jj=0;jj<4;jj++)
      o[rowq*256 + h*64 + 16*jj + l15] = f2bf(acc[jj][r]*inv);
  }
}

// ---------------- SE gate helpers ----------------
__global__ void semean1_k(const float* __restrict__ x, float* __restrict__ part){
  const int blk = blockIdx.x; const int b = blk>>3, sl = blk&7;
  const int t = threadIdx.x;
  const float* p = x + ((long)b*1024 + sl*128)*256 + t;
  float s=0.f;
  for (int i=0;i<128;i++) s += p[(long)i*256];
  part[(long)blk*256 + t] = s;
}

__global__ void semean2_k(const float* __restrict__ part, float* __restrict__ cm){
  const int b = blockIdx.x, t = threadIdx.x;
  float s=0.f;
  for (int i=0;i<8;i++) s += part[(long)(b*8+i)*256 + t];
  cm[b*256+t] = s*(1.f/1024.f);
}

__global__ void segate_k(const float* __restrict__ cm, const float* __restrict__ w1,
                         const float* __restrict__ w2, float* __restrict__ gate){
  const int b = blockIdx.x, t = threadIdx.x;
  __shared__ float sc[256], sh[64];
  sc[t] = cm[b*256+t];
  __syncthreads();
  if (t < 64){
    float s=0.f;
    for (int k=0;k<256;k++) s += sc[k]*w1[k*64+t];
    sh[t] = fmaxf(s, 0.f);
  }
  __syncthreads();
  float s=0.f;
  for (int k=0;k<64;k++) s += sh[k]*w2[k*256+t];
  gate[b*256+t] = 1.f/(1.f+__expf(-s));
}

__global__ void seapply_k(float* __restrict__ x, const float* __restrict__ gate){
  long o4 = ((long)blockIdx.x*256 + threadIdx.x)*4;
  float4 v = *reinterpret_cast<float4*>(x+o4);
  float4 g = *reinterpret_cast<const float4*>(gate + (((o4>>18)<<8) | (o4 & 255)));
  v.x*=g.x; v.y*=g.y; v.z*=g.z; v.w*=g.w;
  *reinterpret_cast<float4*>(x+o4) = v;
}

// ---------------- depthwise conv + BN + GELU -> bf16 ----------------
__global__ void conv_bf_k(const float* __restrict__ y, unsigned short* __restrict__ z,
   const float* __restrict__ wh, const float* __restrict__ bh,
   const float* __restrict__ wv, const float* __restrict__ bv,
   const float* __restrict__ g, const float* __restrict__ bb,
   const float* __restrict__ mm, const float* __restrict__ vv)
{
  const int row = blockIdx.x;
  const int n = row & 1023;
  const float* yr = y + (long)row*512;
  for (int j=threadIdx.x; j<512; j+=256){
    float yc = yr[j];
    float ym = (n>0)   ? yr[j-512] : 0.f;
    float yp = (n<1023)? yr[j+512] : 0.f;
    float chv = wh[j*3+0]*ym + wh[j*3+1]*yc + wh[j*3+2]*yp + bh[j];
    float cvv = wv[j*3+1]*yc + bv[j];
    float zz = chv + cvv;
    zz = (zz - mm[j])*rsqrtf(vv[j]+EPSF)*g[j] + bb[j];
    z[(long)row*512 + j] = f2bf(gelu_f(zz));
  }
}

extern "C" void kernel_launch(void* const* d_in, const int* in_sizes, int n_in,
                              void* d_out, int out_size, void* d_ws, size_t ws_size,
                              hipStream_t stream)
{
  const float* x_in  = (const float*)d_in[0];
  const float* ln1_g = (const float*)d_in[1];
  const float* ln1_b = (const float*)d_in[2];
  const float* w_qkv = (const float*)d_in[3];
  const float* w_out = (const float*)d_in[4];
  const float* b_out = (const float*)d_in[5];
  const float* ln2_g = (const float*)d_in[6];
  const float* ln2_b = (const float*)d_in[7];
  const float* w_fc1 = (const float*)d_in[8];
  const float* b_fc1 = (const float*)d_in[9];
  const float* wh    = (const float*)d_in[10];
  const float* bh    = (const float*)d_in[11];
  const float* wv    = (const float*)d_in[12];
  const float* bv    = (const float*)d_in[13];
  const float* bn_g  = (const float*)d_in[14];
  const float* bn_b  = (const float*)d_in[15];
  const float* bn_m  = (const float*)d_in[16];
  const float* bn_v  = (const float*)d_in[17];
  const float* w_fc2 = (const float*)d_in[18];
  const float* b_fc2 = (const float*)d_in[19];
  const float* ls_w1 = (const float*)d_in[20];
  const float* ls_w2 = (const float*)d_in[21];

  float* ws   = (float*)d_ws;
  float* xbuf = ws;                      // 2,097,152 fl
  float* ybuf = xbuf + 2097152;          // 4,194,304 fl
  float* partial = ybuf + 4194304;       // 16,384
  float* cm   = partial + 16384;         // 2,048
  float* gate = cm + 2048;               // 2,048
  unsigned short* habf = (unsigned short*)(gate + 2048);   // 2,097,152 sh
  unsigned short* qkvb = habf + 2097152;                   // 6,291,456 sh
  unsigned short* zbf  = qkvb + 6291456;                   // 4,194,304 sh
  unsigned short* wqkv_t = zbf + 4194304;                  // 2*768*256
  unsigned short* wout_t = wqkv_t + 2*768*256;
  unsigned short* wfc1_t = wout_t + 2*256*256;
  unsigned short* wfc2_t = wfc1_t + 2*512*256;

  copy4_k<<<2048,256,0,stream>>>(x_in, xbuf);

  for (int l=0;l<2;l++){
    tcast_k<<<(768*256+255)/256,256,0,stream>>>(w_qkv + (long)l*256*768, wqkv_t + (long)l*768*256, 256, 768);
    tcast_k<<<(256*256+255)/256,256,0,stream>>>(w_out + (long)l*256*256, wout_t + (long)l*256*256, 256, 256);
    tcast_k<<<(512*256+255)/256,256,0,stream>>>(w_fc1 + (long)l*256*512, wfc1_t + (long)l*512*256, 256, 512);
    tcast_k<<<(256*512+255)/256,256,0,stream>>>(w_fc2 + (long)l*512*256, wfc2_t + (long)l*256*512, 512, 256);
  }

  for (int l=0;l<2;l++){
    const float* bout_l = b_out + l*256;
    const float* bfc1_l = b_fc1 + l*512;
    const float* bfc2_l = b_fc2 + l*256;
    const float* lw1_l  = ls_w1 + (long)l*256*64;
    const float* lw2_l  = ls_w2 + (long)l*64*256;

    // --- MHSA ---
    ln_bf_k<<<8192,256,0,stream>>>(xbuf, ln1_g + l*256, ln1_b + l*256, habf);
    gmm_k<0,false,false,true><<<dim3(6,64),256,0,stream>>>(
        habf, wqkv_t + (long)l*768*256, (void*)qkvb, 768, nullptr, nullptr, 256);
    attn_k<<<dim3(16,32),256,0,stream>>>(qkvb, habf);   // bf16 out, overwrites LN buf
    gmm_k<0,true,true,false><<<dim3(2,64),256,0,stream>>>(
        habf, wout_t + (long)l*256*256, (void*)xbuf, 256, bout_l, xbuf, 256);

    semean1_k<<<64,256,0,stream>>>(xbuf, partial);
    semean2_k<<<8,256,0,stream>>>(partial, cm);
    segate_k<<<8,256,0,stream>>>(cm, lw1_l, lw2_l, gate);
    seapply_k<<<2048,256,0,stream>>>(xbuf, gate);

    // --- MLP ---
    ln_bf_k<<<8192,256,0,stream>>>(xbuf, ln2_g + l*256, ln2_b + l*256, habf);
    gmm_k<1,false,true,false><<<dim3(4,64),256,0,stream>>>(
        habf, wfc1_t + (long)l*512*256, (void*)ybuf, 512, bfc1_l, nullptr, 256);
    conv_bf_k<<<8192,256,0,stream>>>(ybuf, zbf, wh + (long)l*512*3, bh + l*512,
        wv + (long)l*512*3, bv + l*512, bn_g + l*512, bn_b + l*512,
        bn_m + l*512, bn_v + l*512);
    gmm_k<0,true,true,false><<<dim3(2,64),256,0,stream>>>(
        zbf, wfc2_t + (long)l*256*512, (void*)xbuf, 256, bfc2_l, xbuf, 512);

    semean1_k<<<64,256,0,stream>>>(xbuf, partial);
    semean2_k<<<8,256,0,stream>>>(partial, cm);
    segate_k<<<8,256,0,stream>>>(cm, lw1_l, lw2_l, gate);
    seapply_k<<<2048,256,0,stream>>>(xbuf, gate);
  }

  copy4_k<<<2048,256,0,stream>>>(xbuf, (float*)d_out);
}

// Round 9
// 416.575 us; speedup vs baseline: 3.1013x; 1.0852x over previous
//
#include <hip/hip_runtime.h>
#include <hip/hip_bf16.h>
#include <math.h>

#define EPSF 1e-5f

typedef short bf16x8 __attribute__((ext_vector_type(8)));
typedef float f32x4  __attribute__((ext_vector_type(4)));

__device__ __forceinline__ float gelu_f(float z){
  return 0.5f*z*(1.0f + erff(z*0.70710678118654752f));
}
__device__ __forceinline__ unsigned short f2bf(float f){
  unsigned u = __float_as_uint(f);
  u += 0x7FFFu + ((u >> 16) & 1u);
  return (unsigned short)(u >> 16);
}
__device__ __forceinline__ float bf2f(unsigned short u){
  return __uint_as_float((unsigned)u << 16);
}
// async global->LDS, 16B per lane, lane-contiguous LDS destination
__device__ __forceinline__ void gll16(const unsigned short* g, unsigned short* l){
  __builtin_amdgcn_global_load_lds(
    (const __attribute__((address_space(1))) unsigned int*)g,
    (__attribute__((address_space(3))) unsigned int*)l, 16, 0, 0);
}

// ---------------- all-weight transpose+cast: fp32 [K][N] -> bf16 [N][K] ----------------
__global__ void tcast_all_k(const float* __restrict__ wqkv, const float* __restrict__ wout,
                            const float* __restrict__ wfc1, const float* __restrict__ wfc2,
                            unsigned short* __restrict__ oqkv, unsigned short* __restrict__ oout,
                            unsigned short* __restrict__ ofc1, unsigned short* __restrict__ ofc2){
  int idx = blockIdx.x*256 + threadIdx.x;          // 2*524288 total
  int l = idx >> 19; int r = idx & 524287;
  const float* in; unsigned short* out; int K, N, base;
  if (r < 196608)      { in=wqkv+ (long)l*196608; out=oqkv+(long)l*196608; K=256; N=768; base=r; }
  else if (r < 262144) { in=wout+ (long)l*65536;  out=oout+(long)l*65536;  K=256; N=256; base=r-196608; }
  else if (r < 393216) { in=wfc1+ (long)l*131072; out=ofc1+(long)l*131072; K=256; N=512; base=r-262144; }
  else                 { in=wfc2+ (long)l*131072; out=ofc2+(long)l*131072; K=512; N=256; base=r-393216; }
  int n = base / K, k = base % K;
  out[base] = f2bf(in[(long)k*N + n]);
}

// ---------------- LayerNorm -> bf16 ----------------
__global__ void ln_bf_k(const float* __restrict__ x, const float* __restrict__ g,
                        const float* __restrict__ b, unsigned short* __restrict__ out){
  const int row = blockIdx.x;
  const int t = threadIdx.x;
  float v = x[(long)row*256 + t];
  float s = v, s2 = v*v;
  for (int o=32;o>0;o>>=1){ s += __shfl_down(s,o); s2 += __shfl_down(s2,o); }
  __shared__ float ls[4], ls2[4];
  const int w = t>>6, lane = t&63;
  if (lane==0){ ls[w]=s; ls2[w]=s2; }
  __syncthreads();
  if (t==0){
    float a  = ls[0]+ls[1]+ls[2]+ls[3];
    float a2 = ls2[0]+ls2[1]+ls2[2]+ls2[3];
    float mu = a*(1.f/256.f);
    float var = a2*(1.f/256.f) - mu*mu;
    ls[0]=mu; ls2[0]=rsqrtf(var+EPSF);
  }
  __syncthreads();
  out[(long)row*256+t] = f2bf((v-ls[0])*ls2[0]*g[t] + b[t]);
}

// ---------------- SE-apply + LayerNorm fused (gated x kept as residual) ----------------
__global__ void seapply_ln_k(float* __restrict__ x, const float* __restrict__ gate,
                             const float* __restrict__ g, const float* __restrict__ b,
                             unsigned short* __restrict__ out){
  const int row = blockIdx.x;
  const int t = threadIdx.x;
  const int bi = row >> 10;
  float v = x[(long)row*256 + t] * gate[bi*256 + t];
  x[(long)row*256 + t] = v;
  float s = v, s2 = v*v;
  for (int o=32;o>0;o>>=1){ s += __shfl_down(s,o); s2 += __shfl_down(s2,o); }
  __shared__ float ls[4], ls2[4];
  const int w = t>>6, lane = t&63;
  if (lane==0){ ls[w]=s; ls2[w]=s2; }
  __syncthreads();
  if (t==0){
    float a  = ls[0]+ls[1]+ls[2]+ls[3];
    float a2 = ls2[0]+ls2[1]+ls2[2]+ls2[3];
    float mu = a*(1.f/256.f);
    float var = a2*(1.f/256.f) - mu*mu;
    ls[0]=mu; ls2[0]=rsqrtf(var+EPSF);
  }
  __syncthreads();
  out[(long)row*256+t] = f2bf((v-ls[0])*ls2[0]*g[t] + b[t]);
}

// ---------------- final SE-apply -> d_out fp32 ----------------
__global__ void seapply_out_k(const float* __restrict__ x, const float* __restrict__ gate,
                              float* __restrict__ o){
  long o4 = ((long)blockIdx.x*256 + threadIdx.x)*4;
  float4 v = *reinterpret_cast<const float4*>(x+o4);
  float4 g = *reinterpret_cast<const float4*>(gate + (((o4>>18)<<8) | (o4 & 255)));
  v.x*=g.x; v.y*=g.y; v.z*=g.z; v.w*=g.w;
  *reinterpret_cast<float4*>(o+o4) = v;
}

// ---------------- bf16 MFMA GEMM with global_load_lds staging ----------------
// A: [M][K] bf16. Bt: [N][K] bf16. OUT: 0=fp32, 1=bf16, 2=qkv-special (qkb+vtb).
// BNT: 128 or 64. grid (N/BNT, M/128), block 256.
template<int ACT, bool RES, bool BIAS, int OUT, int BNT>
__global__ __launch_bounds__(256,2)
void gmm_k(const unsigned short* __restrict__ A,
           const unsigned short* __restrict__ Bt,
           void* __restrict__ Cv, int ldc,
           const float* __restrict__ bias,
           const float* __restrict__ res,
           int K, unsigned short* __restrict__ vtb)
{
  __shared__ unsigned short As[128*64];
  __shared__ unsigned short Bs[BNT*64];
  float* C = (float*)Cv;
  unsigned short* Cb = (unsigned short*)Cv;
  const int tid  = threadIdx.x;
  const int wave = tid>>6, lane = tid&63;
  constexpr int NJ = (BNT==128) ? 4 : 2;
  const int wm = (wave>>1)*64, wn = (wave&1)*(BNT/2);
  const int m0 = blockIdx.y*128, n0 = blockIdx.x*BNT;
  const int lrow = lane&15, quad = lane>>4;

  f32x4 acc[4][NJ];
  #pragma unroll
  for (int i=0;i<4;i++)
    #pragma unroll
    for (int j=0;j<NJ;j++)
      #pragma unroll
      for (int r=0;r<4;r++) acc[i][j][r]=0.f;

  for (int k0=0;k0<K;k0+=64){
    __syncthreads();
    #pragma unroll
    for (int it=0; it<4; it++){
      int idx = tid + it*256;
      int row = idx>>3, c = idx&7;
      gll16(A + (long)(m0+row)*K + k0 + c*8, &As[idx*8]);
    }
    #pragma unroll
    for (int it=0; it<BNT/32; it++){
      int idx = tid + it*256;
      int row = idx>>3, c = idx&7;
      gll16(Bt + (long)(n0+row)*K + k0 + c*8, &Bs[idx*8]);
    }
    __syncthreads();
    #pragma unroll
    for (int s=0;s<2;s++){
      bf16x8 a[4], b[NJ];
      const int ck = s*4 + quad;
      #pragma unroll
      for (int i=0;i<4;i++)
        a[i] = *reinterpret_cast<const bf16x8*>(&As[(wm+16*i+lrow)*64 + ck*8]);
      #pragma unroll
      for (int j=0;j<NJ;j++)
        b[j] = *reinterpret_cast<const bf16x8*>(&Bs[(wn+16*j+lrow)*64 + ck*8]);
      #pragma unroll
      for (int i=0;i<4;i++)
        #pragma unroll
        for (int j=0;j<NJ;j++)
          acc[i][j] = __builtin_amdgcn_mfma_f32_16x16x32_bf16(a[i], b[j], acc[i][j], 0,0,0);
    }
  }

  #pragma unroll
  for (int i=0;i<4;i++){
    const int row0 = m0 + wm + 16*i + quad*4;
    #pragma unroll
    for (int j=0;j<NJ;j++){
      const int col = n0 + wn + 16*j + lrow;
      if (OUT==2){
        if (col < 512){
          #pragma unroll
          for (int r=0;r<4;r++)
            Cb[(long)(row0+r)*512 + col] = f2bf(acc[i][j][r]);
        } else {
          ushort4 u;
          u.x = f2bf(acc[i][j][0]); u.y = f2bf(acc[i][j][1]);
          u.z = f2bf(acc[i][j][2]); u.w = f2bf(acc[i][j][3]);
          int bb = row0 >> 10, nn = row0 & 1023;
          int h = (col-512) >> 6, d = (col-512) & 63;
          *reinterpret_cast<ushort4*>(&vtb[(long)((bb*4+h)*64 + d)*1024 + nn]) = u;
        }
      } else {
        const float bv = BIAS ? bias[col] : 0.f;
        #pragma unroll
        for (int r=0;r<4;r++){
          const long off = (long)(row0+r)*ldc + col;
          float v = acc[i][j][r] + bv;
          if (RES) v += res[off];
          if (ACT==1) v = gelu_f(v);
          if (OUT==1) Cb[off] = f2bf(v); else C[off] = v;
        }
      }
    }
  }
}

// ---------------- MFMA flash attention (bf16, V pre-transposed) ----------------
// qkb: [B*N][512] bf16 (q 0..255, k 256..511; col=h*64+d)
// vtb: [32 bh][64 d][1024 n] bf16.  o: [B*N][256] bf16 merged.
// grid (16 q-tiles, 32 bh), block 256 (4 waves x 16 q-rows).
__global__ __launch_bounds__(256)
void attn_k(const unsigned short* __restrict__ qkb,
            const unsigned short* __restrict__ vtb,
            unsigned short* __restrict__ o){
  const int q0 = blockIdx.x * 64;
  const int bh = blockIdx.y;
  const int b = bh >> 2, h = bh & 3;
  const int tid = threadIdx.x;
  const int wv = tid >> 6;
  const int lane = tid & 63;
  const int l15 = lane & 15, quad = lane >> 4;

  __shared__ unsigned short Qs[64*64];   // [qrow][d], granule ^(row&7)
  __shared__ unsigned short Ks[64*64];   // [key][d],  granule ^(key&7)
  __shared__ unsigned short Vt[64*64];   // [d][key],  granule ^(d&7)
  __shared__ unsigned short Ps[64*64];   // [qrow][key], granule ^((row>>2)&7)

  const long rowbase = (long)b*1024;
  const unsigned short* vsrc = vtb + (long)bh*64*1024;

  for (int f = tid; f < 512; f += 256){
    int row = f >> 3, g = f & 7;
    *reinterpret_cast<uint4*>(&Qs[row*64 + (g ^ (row&7))*8]) =
      *reinterpret_cast<const uint4*>(qkb + (rowbase + q0 + row)*512 + h*64 + g*8);
  }

  float m_i[4], l_i[4];
  f32x4 acc[4];
  #pragma unroll
  for (int r=0;r<4;r++){ m_i[r] = -1e30f; l_i[r] = 0.f; }
  #pragma unroll
  for (int j=0;j<4;j++)
    #pragma unroll
    for (int r=0;r<4;r++) acc[j][r] = 0.f;

  for (int k0 = 0; k0 < 1024; k0 += 64){
    __syncthreads();
    for (int f = tid; f < 512; f += 256){
      int row = f >> 3, g = f & 7;
      *reinterpret_cast<uint4*>(&Ks[row*64 + (g ^ (row&7))*8]) =
        *reinterpret_cast<const uint4*>(qkb + (rowbase + k0 + row)*512 + 256 + h*64 + g*8);
      *reinterpret_cast<uint4*>(&Vt[row*64 + (g ^ (row&7))*8]) =
        *reinterpret_cast<const uint4*>(vsrc + (long)row*1024 + k0 + g*8);
    }
    __syncthreads();

    f32x4 s[4];
    #pragma unroll
    for (int j=0;j<4;j++)
      #pragma unroll
      for (int r=0;r<4;r++) s[j][r] = 0.f;

    #pragma unroll
    for (int half=0; half<2; half++){
      const int ck = half*4 + quad;
      const int qrow = 16*wv + l15;
      bf16x8 a = *reinterpret_cast<const bf16x8*>(&Qs[qrow*64 + (ck ^ (qrow&7))*8]);
      #pragma unroll
      for (int j=0;j<4;j++){
        int krow = 16*j + l15;
        bf16x8 bb = *reinterpret_cast<const bf16x8*>(&Ks[krow*64 + (ck ^ (krow&7))*8]);
        s[j] = __builtin_amdgcn_mfma_f32_16x16x32_bf16(a, bb, s[j], 0,0,0);
      }
    }

    #pragma unroll
    for (int r=0;r<4;r++){
      float mx = -1e30f;
      #pragma unroll
      for (int j=0;j<4;j++){ s[j][r] *= 0.125f; mx = fmaxf(mx, s[j][r]); }
      #pragma unroll
      for (int off=8; off>0; off>>=1) mx = fmaxf(mx, __shfl_xor(mx, off));
      const float mnew = fmaxf(m_i[r], mx);
      const float alpha = __expf(m_i[r] - mnew);
      m_i[r] = mnew;
      float rs = 0.f;
      #pragma unroll
      for (int j=0;j<4;j++){ float p = __expf(s[j][r]-mnew); s[j][r] = p; rs += p; }
      #pragma unroll
      for (int off=8; off>0; off>>=1) rs += __shfl_xor(rs, off);
      l_i[r] = l_i[r]*alpha + rs;
      #pragma unroll
      for (int j=0;j<4;j++) acc[j][r] *= alpha;
    }

    #pragma unroll
    for (int j=0;j<4;j++)
      #pragma unroll
      for (int r=0;r<4;r++){
        int rowq = 16*wv + quad*4 + r;
        int key = l15 + 16*j;
        Ps[rowq*64 + (((key>>3) ^ ((rowq>>2)&7)))*8 + (key&7)] = f2bf(s[j][r]);
      }

    #pragma unroll
    for (int half=0; half<2; half++){
      const int ck = half*4 + quad;
      const int prow = 16*wv + l15;
      bf16x8 a = *reinterpret_cast<const bf16x8*>(&Ps[prow*64 + (ck ^ ((prow>>2)&7))*8]);
      #pragma unroll
      for (int jj=0;jj<4;jj++){
        int drow = 16*jj + l15;
        bf16x8 bb = *reinterpret_cast<const bf16x8*>(&Vt[drow*64 + (ck ^ (drow&7))*8]);
        acc[jj] = __builtin_amdgcn_mfma_f32_16x16x32_bf16(a, bb, acc[jj], 0,0,0);
      }
    }
  }

  #pragma unroll
  for (int r=0;r<4;r++){
    const float inv = 1.f / l_i[r];
    const long rowq = rowbase + q0 + 16*wv + quad*4 + r;
    #pragma unroll
    for (int jj=0;jj<4;jj++)
      o[rowq*256 + h*64 + 16*jj + l15] = f2bf(acc[jj][r]*inv);
  }
}

// ---------------- SE mean stage 1 ----------------
__global__ void semean1_k(const float* __restrict__ x, float* __restrict__ part){
  const int blk = blockIdx.x; const int b = blk>>3, sl = blk&7;
  const int t = threadIdx.x;
  const float* p = x + ((long)b*1024 + sl*128)*256 + t;
  float s=0.f;
  for (int i=0;i<128;i++) s += p[(long)i*256];
  part[(long)blk*256 + t] = s;
}

// ---------------- SE mean stage 2 + gate ----------------
__global__ void segate2_k(const float* __restrict__ part, const float* __restrict__ w1,
                          const float* __restrict__ w2, float* __restrict__ gate){
  const int b = blockIdx.x, t = threadIdx.x;
  __shared__ float sc[256], sh[64];
  float s=0.f;
  for (int i=0;i<8;i++) s += part[(long)(b*8+i)*256 + t];
  sc[t] = s*(1.f/1024.f);
  __syncthreads();
  if (t < 64){
    float a=0.f;
    for (int k=0;k<256;k++) a += sc[k]*w1[k*64+t];
    sh[t] = fmaxf(a, 0.f);
  }
  __syncthreads();
  float a=0.f;
  for (int k=0;k<64;k++) a += sh[k]*w2[k*256+t];
  gate[b*256+t] = 1.f/(1.f+__expf(-a));
}

// ---------------- depthwise conv + BN + GELU (bf16 in/out) ----------------
__global__ void conv_bf_k(const unsigned short* __restrict__ y, unsigned short* __restrict__ z,
   const float* __restrict__ wh, const float* __restrict__ bh,
   const float* __restrict__ wv, const float* __restrict__ bv,
   const float* __restrict__ g, const float* __restrict__ bb,
   const float* __restrict__ mm, const float* __restrict__ vv)
{
  const int row = blockIdx.x;
  const int n = row & 1023;
  const unsigned short* yr = y + (long)row*512;
  for (int j=threadIdx.x; j<512; j+=256){
    float yc = bf2f(yr[j]);
    float ym = (n>0)   ? bf2f(yr[j-512]) : 0.f;
    float yp = (n<1023)? bf2f(yr[j+512]) : 0.f;
    float chv = wh[j*3+0]*ym + wh[j*3+1]*yc + wh[j*3+2]*yp + bh[j];
    float cvv = wv[j*3+1]*yc + bv[j];
    float zz = chv + cvv;
    zz = (zz - mm[j])*rsqrtf(vv[j]+EPSF)*g[j] + bb[j];
    z[(long)row*512 + j] = f2bf(gelu_f(zz));
  }
}

extern "C" void kernel_launch(void* const* d_in, const int* in_sizes, int n_in,
                              void* d_out, int out_size, void* d_ws, size_t ws_size,
                              hipStream_t stream)
{
  const float* x_in  = (const float*)d_in[0];
  const float* ln1_g = (const float*)d_in[1];
  const float* ln1_b = (const float*)d_in[2];
  const float* w_qkv = (const float*)d_in[3];
  const float* w_out = (const float*)d_in[4];
  const float* b_out = (const float*)d_in[5];
  const float* ln2_g = (const float*)d_in[6];
  const float* ln2_b = (const float*)d_in[7];
  const float* w_fc1 = (const float*)d_in[8];
  const float* b_fc1 = (const float*)d_in[9];
  const float* wh    = (const float*)d_in[10];
  const float* bh    = (const float*)d_in[11];
  const float* wv    = (const float*)d_in[12];
  const float* bv    = (const float*)d_in[13];
  const float* bn_g  = (const float*)d_in[14];
  const float* bn_b  = (const float*)d_in[15];
  const float* bn_m  = (const float*)d_in[16];
  const float* bn_v  = (const float*)d_in[17];
  const float* w_fc2 = (const float*)d_in[18];
  const float* b_fc2 = (const float*)d_in[19];
  const float* ls_w1 = (const float*)d_in[20];
  const float* ls_w2 = (const float*)d_in[21];

  float* ws   = (float*)d_ws;
  float* xbuf = ws;                      // 2,097,152 fl
  float* partial = xbuf + 2097152;       // 16,384
  float* gate = partial + 16384;         // 2,048
  unsigned short* habf = (unsigned short*)(gate + 2048);   // 2,097,152 u16
  unsigned short* qkb  = habf + 2097152;                   // 4,194,304 u16 [8192][512]
  unsigned short* vtb  = qkb  + 4194304;                   // 2,097,152 u16 [32][64][1024]
  unsigned short* ybf  = vtb  + 2097152;                   // 4,194,304 u16
  unsigned short* zbf  = ybf  + 4194304;                   // 4,194,304 u16
  unsigned short* wqkv_t = zbf + 4194304;                  // 393,216
  unsigned short* wout_t = wqkv_t + 393216;                // 131,072
  unsigned short* wfc1_t = wout_t + 131072;                // 262,144
  unsigned short* wfc2_t = wfc1_t + 262144;                // 262,144

  tcast_all_k<<<4096,256,0,stream>>>(w_qkv, w_out, w_fc1, w_fc2,
                                     wqkv_t, wout_t, wfc1_t, wfc2_t);

  for (int l=0;l<2;l++){
    const float* bout_l = b_out + l*256;
    const float* bfc1_l = b_fc1 + l*512;
    const float* bfc2_l = b_fc2 + l*256;
    const float* lw1_l  = ls_w1 + (long)l*256*64;
    const float* lw2_l  = ls_w2 + (long)l*64*256;
    const float* resx   = (l==0) ? x_in : xbuf;

    // --- MHSA ---
    if (l==0)
      ln_bf_k<<<8192,256,0,stream>>>(x_in, ln1_g, ln1_b, habf);
    // (for l==1, habf was produced by the previous seapply_ln with ln1[1])
    gmm_k<0,false,false,2,128><<<dim3(6,64),256,0,stream>>>(
        habf, wqkv_t + (long)l*768*256, (void*)qkb, 512, nullptr, nullptr, 256, vtb);
    attn_k<<<dim3(16,32),256,0,stream>>>(qkb, vtb, habf);
    gmm_k<0,true,true,0,64><<<dim3(4,64),256,0,stream>>>(
        habf, wout_t + (long)l*256*256, (void*)xbuf, 256, bout_l, resx, 256, nullptr);

    semean1_k<<<64,256,0,stream>>>(xbuf, partial);
    segate2_k<<<8,256,0,stream>>>(partial, lw1_l, lw2_l, gate);
    seapply_ln_k<<<8192,256,0,stream>>>(xbuf, gate, ln2_g + l*256, ln2_b + l*256, habf);

    // --- MLP ---
    gmm_k<1,false,true,1,128><<<dim3(4,64),256,0,stream>>>(
        habf, wfc1_t + (long)l*512*256, (void*)ybf, 512, bfc1_l, nullptr, 256, nullptr);
    conv_bf_k<<<8192,256,0,stream>>>(ybf, zbf, wh + (long)l*512*3, bh + l*512,
        wv + (long)l*512*3, bv + l*512, bn_g + l*512, bn_b + l*512,
        bn_m + l*512, bn_v + l*512);
    gmm_k<0,true,true,0,64><<<dim3(4,64),256,0,stream>>>(
        zbf, wfc2_t + (long)l*256*512, (void*)xbuf, 256, bfc2_l, xbuf, 512, nullptr);

    semean1_k<<<64,256,0,stream>>>(xbuf, partial);
    segate2_k<<<8,256,0,stream>>>(partial, lw1_l, lw2_l, gate);
    if (l==0)
      seapply_ln_k<<<8192,256,0,stream>>>(xbuf, gate, ln1_g + 256, ln1_b + 256, habf);
    else
      seapply_out_k<<<2048,256,0,stream>>>(xbuf, gate, (float*)d_out);
  }
}

// Round 10
// 399.550 us; speedup vs baseline: 3.2334x; 1.0426x over previous
//
#include <hip/hip_runtime.h>
#include <hip/hip_bf16.h>
#include <math.h>

#define EPSF 1e-5f

typedef short bf16x8 __attribute__((ext_vector_type(8)));
typedef float f32x4  __attribute__((ext_vector_type(4)));

__device__ __forceinline__ float gelu_f(float z){
  return 0.5f*z*(1.0f + erff(z*0.70710678118654752f));
}
__device__ __forceinline__ unsigned short f2bf(float f){
  unsigned u = __float_as_uint(f);
  u += 0x7FFFu + ((u >> 16) & 1u);
  return (unsigned short)(u >> 16);
}
__device__ __forceinline__ float bf2f(unsigned short u){
  return __uint_as_float((unsigned)u << 16);
}
__device__ __forceinline__ void gll16(const unsigned short* g, unsigned short* l){
  __builtin_amdgcn_global_load_lds(
    (const __attribute__((address_space(1))) unsigned int*)g,
    (__attribute__((address_space(3))) unsigned int*)l, 16, 0, 0);
}

// ---------------- all-weight transpose+cast: fp32 [K][N] -> bf16 [N][K] ----------------
__global__ void tcast_all_k(const float* __restrict__ wqkv, const float* __restrict__ wout,
                            const float* __restrict__ wfc1, const float* __restrict__ wfc2,
                            unsigned short* __restrict__ oqkv, unsigned short* __restrict__ oout,
                            unsigned short* __restrict__ ofc1, unsigned short* __restrict__ ofc2){
  int idx = blockIdx.x*256 + threadIdx.x;
  int l = idx >> 19; int r = idx & 524287;
  const float* in; unsigned short* out; int K, N, base;
  if (r < 196608)      { in=wqkv+ (long)l*196608; out=oqkv+(long)l*196608; K=256; N=768; base=r; }
  else if (r < 262144) { in=wout+ (long)l*65536;  out=oout+(long)l*65536;  K=256; N=256; base=r-196608; }
  else if (r < 393216) { in=wfc1+ (long)l*131072; out=ofc1+(long)l*131072; K=256; N=512; base=r-262144; }
  else                 { in=wfc2+ (long)l*131072; out=ofc2+(long)l*131072; K=512; N=256; base=r-393216; }
  int n = base / K, k = base % K;
  out[base] = f2bf(in[(long)k*N + n]);
}

// ---------------- LayerNorm -> bf16 ----------------
__global__ void ln_bf_k(const float* __restrict__ x, const float* __restrict__ g,
                        const float* __restrict__ b, unsigned short* __restrict__ out){
  const int row = blockIdx.x;
  const int t = threadIdx.x;
  float v = x[(long)row*256 + t];
  float s = v, s2 = v*v;
  for (int o=32;o>0;o>>=1){ s += __shfl_down(s,o); s2 += __shfl_down(s2,o); }
  __shared__ float ls[4], ls2[4];
  const int w = t>>6, lane = t&63;
  if (lane==0){ ls[w]=s; ls2[w]=s2; }
  __syncthreads();
  if (t==0){
    float a  = ls[0]+ls[1]+ls[2]+ls[3];
    float a2 = ls2[0]+ls2[1]+ls2[2]+ls2[3];
    float mu = a*(1.f/256.f);
    float var = a2*(1.f/256.f) - mu*mu;
    ls[0]=mu; ls2[0]=rsqrtf(var+EPSF);
  }
  __syncthreads();
  out[(long)row*256+t] = f2bf((v-ls[0])*ls2[0]*g[t] + b[t]);
}

// ---------------- SE-apply + LayerNorm fused ----------------
__global__ void seapply_ln_k(float* __restrict__ x, const float* __restrict__ gate,
                             const float* __restrict__ g, const float* __restrict__ b,
                             unsigned short* __restrict__ out){
  const int row = blockIdx.x;
  const int t = threadIdx.x;
  const int bi = row >> 10;
  float v = x[(long)row*256 + t] * gate[bi*256 + t];
  x[(long)row*256 + t] = v;
  float s = v, s2 = v*v;
  for (int o=32;o>0;o>>=1){ s += __shfl_down(s,o); s2 += __shfl_down(s2,o); }
  __shared__ float ls[4], ls2[4];
  const int w = t>>6, lane = t&63;
  if (lane==0){ ls[w]=s; ls2[w]=s2; }
  __syncthreads();
  if (t==0){
    float a  = ls[0]+ls[1]+ls[2]+ls[3];
    float a2 = ls2[0]+ls2[1]+ls2[2]+ls2[3];
    float mu = a*(1.f/256.f);
    float var = a2*(1.f/256.f) - mu*mu;
    ls[0]=mu; ls2[0]=rsqrtf(var+EPSF);
  }
  __syncthreads();
  out[(long)row*256+t] = f2bf((v-ls[0])*ls2[0]*g[t] + b[t]);
}

// ---------------- final SE-apply -> d_out fp32 ----------------
__global__ void seapply_out_k(const float* __restrict__ x, const float* __restrict__ gate,
                              float* __restrict__ o){
  long o4 = ((long)blockIdx.x*256 + threadIdx.x)*4;
  float4 v = *reinterpret_cast<const float4*>(x+o4);
  float4 g = *reinterpret_cast<const float4*>(gate + (((o4>>18)<<8) | (o4 & 255)));
  v.x*=g.x; v.y*=g.y; v.z*=g.z; v.w*=g.w;
  *reinterpret_cast<float4*>(o+o4) = v;
}

// ---------------- bf16 MFMA GEMM with global_load_lds staging ----------------
// OUT: 0=fp32, 1=bf16, 2=qkv-special. CS: atomic column-sum into cm[b*256+col].
template<int ACT, bool RES, bool BIAS, int OUT, int BNT, bool CS>
__global__ __launch_bounds__(256,2)
void gmm_k(const unsigned short* __restrict__ A,
           const unsigned short* __restrict__ Bt,
           void* __restrict__ Cv, int ldc,
           const float* __restrict__ bias,
           const float* __restrict__ res,
           int K, unsigned short* __restrict__ vtb,
           float* __restrict__ cm)
{
  __shared__ unsigned short As[128*64];
  __shared__ unsigned short Bs[BNT*64];
  float* C = (float*)Cv;
  unsigned short* Cb = (unsigned short*)Cv;
  const int tid  = threadIdx.x;
  const int wave = tid>>6, lane = tid&63;
  constexpr int NJ = (BNT==128) ? 4 : 2;
  const int wm = (wave>>1)*64, wn = (wave&1)*(BNT/2);
  const int m0 = blockIdx.y*128, n0 = blockIdx.x*BNT;
  const int lrow = lane&15, quad = lane>>4;

  f32x4 acc[4][NJ];
  #pragma unroll
  for (int i=0;i<4;i++)
    #pragma unroll
    for (int j=0;j<NJ;j++)
      #pragma unroll
      for (int r=0;r<4;r++) acc[i][j][r]=0.f;

  for (int k0=0;k0<K;k0+=64){
    __syncthreads();
    #pragma unroll
    for (int it=0; it<4; it++){
      int idx = tid + it*256;
      int row = idx>>3, c = idx&7;
      gll16(A + (long)(m0+row)*K + k0 + c*8, &As[idx*8]);
    }
    #pragma unroll
    for (int it=0; it<BNT/32; it++){
      int idx = tid + it*256;
      int row = idx>>3, c = idx&7;
      gll16(Bt + (long)(n0+row)*K + k0 + c*8, &Bs[idx*8]);
    }
    __syncthreads();
    #pragma unroll
    for (int s=0;s<2;s++){
      bf16x8 a[4], b[NJ];
      const int ck = s*4 + quad;
      #pragma unroll
      for (int i=0;i<4;i++)
        a[i] = *reinterpret_cast<const bf16x8*>(&As[(wm+16*i+lrow)*64 + ck*8]);
      #pragma unroll
      for (int j=0;j<NJ;j++)
        b[j] = *reinterpret_cast<const bf16x8*>(&Bs[(wn+16*j+lrow)*64 + ck*8]);
      #pragma unroll
      for (int i=0;i<4;i++)
        #pragma unroll
        for (int j=0;j<NJ;j++)
          acc[i][j] = __builtin_amdgcn_mfma_f32_16x16x32_bf16(a[i], b[j], acc[i][j], 0,0,0);
    }
  }

  float csum[NJ];
  #pragma unroll
  for (int j=0;j<NJ;j++) csum[j] = 0.f;

  #pragma unroll
  for (int i=0;i<4;i++){
    const int row0 = m0 + wm + 16*i + quad*4;
    #pragma unroll
    for (int j=0;j<NJ;j++){
      const int col = n0 + wn + 16*j + lrow;
      if (OUT==2){
        if (col < 512){
          #pragma unroll
          for (int r=0;r<4;r++)
            Cb[(long)(row0+r)*512 + col] = f2bf(acc[i][j][r]);
        } else {
          ushort4 u;
          u.x = f2bf(acc[i][j][0]); u.y = f2bf(acc[i][j][1]);
          u.z = f2bf(acc[i][j][2]); u.w = f2bf(acc[i][j][3]);
          int bb = row0 >> 10, nn = row0 & 1023;
          int h = (col-512) >> 6, d = (col-512) & 63;
          *reinterpret_cast<ushort4*>(&vtb[(long)((bb*4+h)*64 + d)*1024 + nn]) = u;
        }
      } else {
        const float bv = BIAS ? bias[col] : 0.f;
        #pragma unroll
        for (int r=0;r<4;r++){
          const long off = (long)(row0+r)*ldc + col;
          float v = acc[i][j][r] + bv;
          if (RES) v += res[off];
          if (ACT==1) v = gelu_f(v);
          if (CS) csum[j] += v;
          if (OUT==1) Cb[off] = f2bf(v); else C[off] = v;
        }
      }
    }
  }
  if (CS){
    const int bb = m0 >> 10;
    #pragma unroll
    for (int j=0;j<NJ;j++)
      atomicAdd(&cm[bb*256 + n0 + wn + 16*j + lrow], csum[j]);
  }
}

// ---------------- MFMA flash attention, split-K over 2 key-halves ----------------
// qkb: [B*N][512] bf16 (q 0..255, k 256..511). vtb: [32][64][1024] bf16.
// op: [2][8192][256] fp32 unnormalized. ml: [2][32][1024][2] fp32 (m,l).
// grid (16 q-tiles, 32 bh, 2 kz), block 256.
__global__ __launch_bounds__(256)
void attn_k(const unsigned short* __restrict__ qkb,
            const unsigned short* __restrict__ vtb,
            float* __restrict__ op, float* __restrict__ ml){
  const int q0 = blockIdx.x * 64;
  const int bh = blockIdx.y;
  const int kz = blockIdx.z;
  const int b = bh >> 2, h = bh & 3;
  const int tid = threadIdx.x;
  const int wv = tid >> 6;
  const int lane = tid & 63;
  const int l15 = lane & 15, quad = lane >> 4;

  __shared__ unsigned short Qs[64*64];
  __shared__ unsigned short Ks[64*64];
  __shared__ unsigned short Vt[64*64];
  __shared__ unsigned short Ps[64*64];

  const long rowbase = (long)b*1024;
  const unsigned short* vsrc = vtb + (long)bh*64*1024;

  for (int f = tid; f < 512; f += 256){
    int row = f >> 3, g = f & 7;
    *reinterpret_cast<uint4*>(&Qs[row*64 + (g ^ (row&7))*8]) =
      *reinterpret_cast<const uint4*>(qkb + (rowbase + q0 + row)*512 + h*64 + g*8);
  }

  float m_i[4], l_i[4];
  f32x4 acc[4];
  #pragma unroll
  for (int r=0;r<4;r++){ m_i[r] = -1e30f; l_i[r] = 0.f; }
  #pragma unroll
  for (int j=0;j<4;j++)
    #pragma unroll
    for (int r=0;r<4;r++) acc[j][r] = 0.f;

  const int kbeg = kz*512, kend = kbeg + 512;
  for (int k0 = kbeg; k0 < kend; k0 += 64){
    __syncthreads();
    for (int f = tid; f < 512; f += 256){
      int row = f >> 3, g = f & 7;
      *reinterpret_cast<uint4*>(&Ks[row*64 + (g ^ (row&7))*8]) =
        *reinterpret_cast<const uint4*>(qkb + (rowbase + k0 + row)*512 + 256 + h*64 + g*8);
      *reinterpret_cast<uint4*>(&Vt[row*64 + (g ^ (row&7))*8]) =
        *reinterpret_cast<const uint4*>(vsrc + (long)row*1024 + k0 + g*8);
    }
    __syncthreads();

    f32x4 s[4];
    #pragma unroll
    for (int j=0;j<4;j++)
      #pragma unroll
      for (int r=0;r<4;r++) s[j][r] = 0.f;

    #pragma unroll
    for (int half=0; half<2; half++){
      const int ck = half*4 + quad;
      const int qrow = 16*wv + l15;
      bf16x8 a = *reinterpret_cast<const bf16x8*>(&Qs[qrow*64 + (ck ^ (qrow&7))*8]);
      #pragma unroll
      for (int j=0;j<4;j++){
        int krow = 16*j + l15;
        bf16x8 bb = *reinterpret_cast<const bf16x8*>(&Ks[krow*64 + (ck ^ (krow&7))*8]);
        s[j] = __builtin_amdgcn_mfma_f32_16x16x32_bf16(a, bb, s[j], 0,0,0);
      }
    }

    #pragma unroll
    for (int r=0;r<4;r++){
      float mx = -1e30f;
      #pragma unroll
      for (int j=0;j<4;j++){ s[j][r] *= 0.125f; mx = fmaxf(mx, s[j][r]); }
      #pragma unroll
      for (int off=8; off>0; off>>=1) mx = fmaxf(mx, __shfl_xor(mx, off));
      const float mnew = fmaxf(m_i[r], mx);
      const float alpha = __expf(m_i[r] - mnew);
      m_i[r] = mnew;
      float rs = 0.f;
      #pragma unroll
      for (int j=0;j<4;j++){ float p = __expf(s[j][r]-mnew); s[j][r] = p; rs += p; }
      #pragma unroll
      for (int off=8; off>0; off>>=1) rs += __shfl_xor(rs, off);
      l_i[r] = l_i[r]*alpha + rs;
      #pragma unroll
      for (int j=0;j<4;j++) acc[j][r] *= alpha;
    }

    #pragma unroll
    for (int j=0;j<4;j++)
      #pragma unroll
      for (int r=0;r<4;r++){
        int rowq = 16*wv + quad*4 + r;
        int key = l15 + 16*j;
        Ps[rowq*64 + (((key>>3) ^ ((rowq>>2)&7)))*8 + (key&7)] = f2bf(s[j][r]);
      }

    #pragma unroll
    for (int half=0; half<2; half++){
      const int ck = half*4 + quad;
      const int prow = 16*wv + l15;
      bf16x8 a = *reinterpret_cast<const bf16x8*>(&Ps[prow*64 + (ck ^ ((prow>>2)&7))*8]);
      #pragma unroll
      for (int jj=0;jj<4;jj++){
        int drow = 16*jj + l15;
        bf16x8 bb = *reinterpret_cast<const bf16x8*>(&Vt[drow*64 + (ck ^ (drow&7))*8]);
        acc[jj] = __builtin_amdgcn_mfma_f32_16x16x32_bf16(a, bb, acc[jj], 0,0,0);
      }
    }
  }

  #pragma unroll
  for (int r=0;r<4;r++){
    const int rloc = q0 + 16*wv + quad*4 + r;
    const long grow = rowbase + rloc;
    #pragma unroll
    for (int jj=0;jj<4;jj++)
      op[((long)kz*8192 + grow)*256 + h*64 + 16*jj + l15] = acc[jj][r];
    if (l15 == 0){
      float* mlp = ml + (((long)kz*32 + bh)*1024 + rloc)*2;
      mlp[0] = m_i[r]; mlp[1] = l_i[r];
    }
  }
}

// ---------------- merge 2 split-K attention partials -> bf16; zero cm ----------------
__global__ void attn_merge_k(const float* __restrict__ op, const float* __restrict__ ml,
                             unsigned short* __restrict__ o, float* __restrict__ cm){
  if (blockIdx.x == 0){
    for (int i = threadIdx.x; i < 2048; i += 256) cm[i] = 0.f;
  }
  long off = ((long)blockIdx.x*256 + threadIdx.x)*4;
  int row = (int)(off >> 8);
  int col = (int)(off & 255);
  int h = col >> 6;
  int b = row >> 10, n = row & 1023;
  int bh = b*4 + h;
  const float* p0 = ml + ((long)bh*1024 + n)*2;
  const float* p1 = ml + (((long)32 + bh)*1024 + n)*2;
  float m0 = p0[0], l0 = p0[1], m1 = p1[0], l1 = p1[1];
  float M = fmaxf(m0, m1);
  float w0 = __expf(m0 - M), w1 = __expf(m1 - M);
  float inv = 1.f / (l0*w0 + l1*w1);
  float4 a0 = *reinterpret_cast<const float4*>(op + off);
  float4 a1 = *reinterpret_cast<const float4*>(op + 2097152 + off);
  ushort4 u;
  u.x = f2bf((a0.x*w0 + a1.x*w1)*inv);
  u.y = f2bf((a0.y*w0 + a1.y*w1)*inv);
  u.z = f2bf((a0.z*w0 + a1.z*w1)*inv);
  u.w = f2bf((a0.w*w0 + a1.w*w1)*inv);
  *reinterpret_cast<ushort4*>(o + off) = u;
}

// ---------------- SE gate from column sums ----------------
__global__ void segate2_k(const float* __restrict__ cm, const float* __restrict__ w1,
                          const float* __restrict__ w2, float* __restrict__ gate){
  const int b = blockIdx.x, t = threadIdx.x;
  __shared__ float sc[256], sh[64];
  sc[t] = cm[b*256+t]*(1.f/1024.f);
  __syncthreads();
  if (t < 64){
    float a=0.f;
    for (int k=0;k<256;k++) a += sc[k]*w1[k*64+t];
    sh[t] = fmaxf(a, 0.f);
  }
  __syncthreads();
  float a=0.f;
  for (int k=0;k<64;k++) a += sh[k]*w2[k*256+t];
  gate[b*256+t] = 1.f/(1.f+__expf(-a));
}

// ---------------- depthwise conv + BN + GELU (bf16 in/out); zero cm ----------------
__global__ void conv_bf_k(const unsigned short* __restrict__ y, unsigned short* __restrict__ z,
   const float* __restrict__ wh, const float* __restrict__ bh,
   const float* __restrict__ wv, const float* __restrict__ bv,
   const float* __restrict__ g, const float* __restrict__ bb,
   const float* __restrict__ mm, const float* __restrict__ vv,
   float* __restrict__ cm)
{
  if (blockIdx.x == 0){
    for (int i = threadIdx.x; i < 2048; i += 256) cm[i] = 0.f;
  }
  const int row = blockIdx.x;
  const int n = row & 1023;
  const unsigned short* yr = y + (long)row*512;
  for (int j=threadIdx.x; j<512; j+=256){
    float yc = bf2f(yr[j]);
    float ym = (n>0)   ? bf2f(yr[j-512]) : 0.f;
    float yp = (n<1023)? bf2f(yr[j+512]) : 0.f;
    float chv = wh[j*3+0]*ym + wh[j*3+1]*yc + wh[j*3+2]*yp + bh[j];
    float cvv = wv[j*3+1]*yc + bv[j];
    float zz = chv + cvv;
    zz = (zz - mm[j])*rsqrtf(vv[j]+EPSF)*g[j] + bb[j];
    z[(long)row*512 + j] = f2bf(gelu_f(zz));
  }
}

extern "C" void kernel_launch(void* const* d_in, const int* in_sizes, int n_in,
                              void* d_out, int out_size, void* d_ws, size_t ws_size,
                              hipStream_t stream)
{
  const float* x_in  = (const float*)d_in[0];
  const float* ln1_g = (const float*)d_in[1];
  const float* ln1_b = (const float*)d_in[2];
  const float* w_qkv = (const float*)d_in[3];
  const float* w_out = (const float*)d_in[4];
  const float* b_out = (const float*)d_in[5];
  const float* ln2_g = (const float*)d_in[6];
  const float* ln2_b = (const float*)d_in[7];
  const float* w_fc1 = (const float*)d_in[8];
  const float* b_fc1 = (const float*)d_in[9];
  const float* wh    = (const float*)d_in[10];
  const float* bh    = (const float*)d_in[11];
  const float* wv    = (const float*)d_in[12];
  const float* bv    = (const float*)d_in[13];
  const float* bn_g  = (const float*)d_in[14];
  const float* bn_b  = (const float*)d_in[15];
  const float* bn_m  = (const float*)d_in[16];
  const float* bn_v  = (const float*)d_in[17];
  const float* w_fc2 = (const float*)d_in[18];
  const float* b_fc2 = (const float*)d_in[19];
  const float* ls_w1 = (const float*)d_in[20];
  const float* ls_w2 = (const float*)d_in[21];

  float* ws   = (float*)d_ws;
  float* xbuf = ws;                        // 2,097,152 fl
  float* opart= xbuf + 2097152;            // 4,194,304 fl  [2][8192][256]
  float* mlb  = opart + 4194304;           // 131,072 fl
  float* cm   = mlb + 131072;              // 2,048
  float* gate = cm + 2048;                 // 2,048
  unsigned short* habf = (unsigned short*)(gate + 2048);   // 2,097,152 u16
  unsigned short* qkb  = habf + 2097152;                   // 4,194,304 u16
  unsigned short* vtb  = qkb  + 4194304;                   // 2,097,152 u16
  unsigned short* ybf  = vtb  + 2097152;                   // 4,194,304 u16
  unsigned short* zbf  = ybf  + 4194304;                   // 4,194,304 u16
  unsigned short* wqkv_t = zbf + 4194304;                  // 393,216
  unsigned short* wout_t = wqkv_t + 393216;
  unsigned short* wfc1_t = wout_t + 131072;
  unsigned short* wfc2_t = wfc1_t + 262144;

  tcast_all_k<<<4096,256,0,stream>>>(w_qkv, w_out, w_fc1, w_fc2,
                                     wqkv_t, wout_t, wfc1_t, wfc2_t);

  for (int l=0;l<2;l++){
    const float* bout_l = b_out + l*256;
    const float* bfc1_l = b_fc1 + l*512;
    const float* bfc2_l = b_fc2 + l*256;
    const float* lw1_l  = ls_w1 + (long)l*256*64;
    const float* lw2_l  = ls_w2 + (long)l*64*256;
    const float* resx   = (l==0) ? x_in : xbuf;

    // --- MHSA ---
    if (l==0)
      ln_bf_k<<<8192,256,0,stream>>>(x_in, ln1_g, ln1_b, habf);
    gmm_k<0,false,false,2,128,false><<<dim3(6,64),256,0,stream>>>(
        habf, wqkv_t + (long)l*768*256, (void*)qkb, 512, nullptr, nullptr, 256, vtb, nullptr);
    attn_k<<<dim3(16,32,2),256,0,stream>>>(qkb, vtb, opart, mlb);
    attn_merge_k<<<2048,256,0,stream>>>(opart, mlb, habf, cm);   // also zeros cm
    gmm_k<0,true,true,0,64,true><<<dim3(4,64),256,0,stream>>>(
        habf, wout_t + (long)l*256*256, (void*)xbuf, 256, bout_l, resx, 256, nullptr, cm);

    segate2_k<<<8,256,0,stream>>>(cm, lw1_l, lw2_l, gate);
    seapply_ln_k<<<8192,256,0,stream>>>(xbuf, gate, ln2_g + l*256, ln2_b + l*256, habf);

    // --- MLP ---
    gmm_k<1,false,true,1,128,false><<<dim3(4,64),256,0,stream>>>(
        habf, wfc1_t + (long)l*512*256, (void*)ybf, 512, bfc1_l, nullptr, 256, nullptr, nullptr);
    conv_bf_k<<<8192,256,0,stream>>>(ybf, zbf, wh + (long)l*512*3, bh + l*512,
        wv + (long)l*512*3, bv + l*512, bn_g + l*512, bn_b + l*512,
        bn_m + l*512, bn_v + l*512, cm);                          // also zeros cm
    gmm_k<0,true,true,0,64,true><<<dim3(4,64),256,0,stream>>>(
        zbf, wfc2_t + (long)l*256*512, (void*)xbuf, 256, bfc2_l, xbuf, 512, nullptr, cm);

    segate2_k<<<8,256,0,stream>>>(cm, lw1_l, lw2_l, gate);
    if (l==0)
      seapply_ln_k<<<8192,256,0,stream>>>(xbuf, gate, ln1_g + 256, ln1_b + 256, habf);
    else
      seapply_out_k<<<2048,256,0,stream>>>(xbuf, gate, (float*)d_out);
  }
}